// Round 11
// baseline (922.791 us; speedup 1.0000x reference)
//
#include <hip/hip_runtime.h>
#include <stdint.h>

typedef __bf16 bf16;
typedef __attribute__((ext_vector_type(8))) __bf16 bf16x8;
typedef __attribute__((ext_vector_type(4))) float f32x4;

namespace {

constexpr int cB = 4, cT = 4096, cD = 2048, cK = 1024, cH = 16, cKVH = 4, cHD = 128, cFF = 8192;
constexpr int cM = cB * cK;                 // 4096 gathered rows
constexpr int QKVW = cH * cHD + 2 * cKVH * cHD; // 3072

__device__ __forceinline__ void load_lds16(const void* g, void* l) {
  __builtin_amdgcn_global_load_lds((const __attribute__((address_space(1))) void*)g,
                                   (__attribute__((address_space(3))) void*)l, 16, 0, 0);
}

template <int N>
__device__ __forceinline__ void waitcnt_vm() {
  if constexpr (N == 0) asm volatile("s_waitcnt vmcnt(0)" ::: "memory");
  else if constexpr (N == 3) asm volatile("s_waitcnt vmcnt(3)" ::: "memory");
  else if constexpr (N == 4) asm volatile("s_waitcnt vmcnt(4)" ::: "memory");
  else if constexpr (N == 6) asm volatile("s_waitcnt vmcnt(6)" ::: "memory");
  else if constexpr (N == 8) asm volatile("s_waitcnt vmcnt(8)" ::: "memory");
  else if constexpr (N == 9) asm volatile("s_waitcnt vmcnt(9)" ::: "memory");
  else if constexpr (N == 12) asm volatile("s_waitcnt vmcnt(12)" ::: "memory");
  else static_assert(N == 0, "unsupported vmcnt literal");
}

// ---------------- block reduce (256 threads = 4 waves) ----------------
template <int OP>  // 0 = sum, 1 = max
__device__ __forceinline__ float blk_reduce(float v) {
  __shared__ float sm[5];
  const int tid = threadIdx.x, lane = tid & 63, wid = tid >> 6;
#pragma unroll
  for (int o = 32; o; o >>= 1) {
    float o2 = __shfl_down(v, o, 64);
    v = OP ? fmaxf(v, o2) : v + o2;
  }
  if (lane == 0) sm[wid] = v;
  __syncthreads();
  if (tid == 0) {
    float r = sm[0];
#pragma unroll
    for (int i = 1; i < 4; ++i) r = OP ? fmaxf(r, sm[i]) : r + sm[i];
    sm[4] = r;
  }
  __syncthreads();
  float r = sm[4];
  __syncthreads();
  return r;
}

// ================= deep-pipelined 256-row MFMA GEMM: C = A * B^T =================
// A: M x Kd row-major (lda), B: N x Kd row-major (ldb). BM=256, BK=32.
// 8 waves (512 thr), WM x WN wave grid, RING-slot LDS ring, counted vmcnt, raw
// barriers, XOR-swizzled LDS (pre-swizzled global src + swizzled ds_read_b128).
// UNROLL=1: prologue D=RING-1 tiles, main waits (D-1)*L; tail = vmcnt(0) + D computes.
// UNROLL=2 (RING=5): two K-steps per barrier. Iter: stage(t+3),stage(t+4),
//   compute(t),compute(t+1), vmcnt(L) [tiles t+2,t+3 landed], barrier. Slot writes
//   (t+3)%5,(t+4)%5 vs reads t%5,(t+1)%5 -> disjoint; previous pair's reads are
//   behind the barrier. Bridge: stage(KT-1), vmcnt(0), barrier, 4 straight computes.
template <int BN, int WM, int WN, int RING, int UNROLL, class Epi>
__global__ __launch_bounds__(512, 2)
void gemm256(const bf16* __restrict__ A, int lda,
             const bf16* __restrict__ Bm, int ldb,
             int Kd, int GM, Epi epi) {
  constexpr int BM = 256;
  constexpr int FM = BM / WM / 16;
  constexpr int FN = BN / WN / 16;
  constexpr int ACALLS = 2;          // 256 rows * 64B / (512 thr * 16B)
  constexpr int BCALLS = BN / 128;
  constexpr int L = ACALLS + BCALLS; // vmem instrs per K-tile per thread
  constexpr int D = RING - 1;        // UNROLL=1 prefetch depth
  constexpr int SLOTA = BM * 64;     // bytes per A K-tile (BK=32 -> 64B rows)
  constexpr int SLOTB = BN * 64;
  constexpr int SLOT = SLOTA + SLOTB;
  __shared__ __align__(16) char lds[RING * SLOT];

  const int tid = threadIdx.x;
  const int lane = tid & 63;
  const int wid = tid >> 6;
  const int l15 = lane & 15, lq = lane >> 4;
  const int wr = wid / WN, wc = wid % WN;

  // per-XCD contiguous chunk (nwg % 8 == 0 for all our launches)
  const int nwg = gridDim.x;
  const int xcd = blockIdx.x & 7, loc = blockIdx.x >> 3;
  const int wg = xcd * (nwg >> 3) + loc;
  // grouped mapping: 8 bm fastest, then bn
  const int GN = nwg / GM;
  const int per = 8 * GN;
  const int g = wg / per, r = wg % per;
  const int bm = g * 8 + (r & 7);
  const int bn = r >> 3;

  const bf16* Abase = A + (int64_t)bm * BM * lda;
  const bf16* Bbase = Bm + (int64_t)bn * BN * ldb;

  // staging: LDS linear chunk -> pre-swizzled global source
  const bf16* srcA[ACALLS];
  int dstA[ACALLS];
#pragma unroll
  for (int c2 = 0; c2 < ACALLS; ++c2) {
    const int chunk = c2 * 512 + tid;
    const int row = chunk >> 2, pc = chunk & 3;
    const int lc = pc ^ ((row >> 1) & 3);
    srcA[c2] = Abase + (int64_t)row * lda + lc * 8;
    dstA[c2] = chunk * 16;
  }
  const bf16* srcB[BCALLS];
  int dstB[BCALLS];
#pragma unroll
  for (int c2 = 0; c2 < BCALLS; ++c2) {
    const int chunk = c2 * 512 + tid;
    const int row = chunk >> 2, pc = chunk & 3;
    const int lc = pc ^ ((row >> 1) & 3);
    srcB[c2] = Bbase + (int64_t)row * ldb + lc * 8;
    dstB[c2] = chunk * 16;
  }

  // fragment read offsets (swizzled)
  int offA[FM], offB[FN];
#pragma unroll
  for (int m = 0; m < FM; ++m) {
    const int row = wr * (BM / WM) + m * 16 + l15;
    offA[m] = row * 64 + (lq ^ ((row >> 1) & 3)) * 16;
  }
#pragma unroll
  for (int n = 0; n < FN; ++n) {
    const int row = wc * (BN / WN) + n * 16 + l15;
    offB[n] = SLOTA + row * 64 + (lq ^ ((row >> 1) & 3)) * 16;
  }

  const int KT = Kd >> 5;
  auto stage = [&](int t) {
    char* sb = lds + (size_t)(t % RING) * SLOT;
#pragma unroll
    for (int c2 = 0; c2 < ACALLS; ++c2)
      load_lds16(srcA[c2] + t * 32, sb + dstA[c2]);
#pragma unroll
    for (int c2 = 0; c2 < BCALLS; ++c2)
      load_lds16(srcB[c2] + t * 32, sb + SLOTA + dstB[c2]);
  };
  auto compute = [&](int t, f32x4 (&acc)[FM][FN]) {
    const char* sb = lds + (size_t)(t % RING) * SLOT;
    bf16x8 av[FM], bv[FN];
#pragma unroll
    for (int m = 0; m < FM; ++m) av[m] = *(const bf16x8*)(sb + offA[m]);
#pragma unroll
    for (int n = 0; n < FN; ++n) bv[n] = *(const bf16x8*)(sb + offB[n]);
    __builtin_amdgcn_s_setprio(1);
#pragma unroll
    for (int m = 0; m < FM; ++m)
#pragma unroll
      for (int n = 0; n < FN; ++n)
        acc[m][n] = __builtin_amdgcn_mfma_f32_16x16x32_bf16(av[m], bv[n], acc[m][n], 0, 0, 0);
    __builtin_amdgcn_s_setprio(0);
  };

  f32x4 acc[FM][FN] = {};

  if constexpr (UNROLL == 1) {
#pragma unroll
    for (int i = 0; i < D; ++i) stage(i);
    waitcnt_vm<(D - 1) * L>();
    __builtin_amdgcn_s_barrier();
    __builtin_amdgcn_sched_barrier(0);
    for (int t = 0; t < KT - D; ++t) {
      stage(t + D);
      compute(t, acc);
      waitcnt_vm<(D - 1) * L>();
      __builtin_amdgcn_s_barrier();
      __builtin_amdgcn_sched_barrier(0);
    }
    // tail: all remaining tiles staged; one full drain, then straight computes
    waitcnt_vm<0>();
    __builtin_amdgcn_s_barrier();
    for (int t = KT - D; t < KT; ++t) compute(t, acc);
  } else {
    static_assert(RING == 5 && UNROLL == 2, "pair mode is RING=5");
#pragma unroll
    for (int i = 0; i < 3; ++i) stage(i);
    waitcnt_vm<L>();  // tiles 0,1 landed (tile 2 may be in flight)
    __builtin_amdgcn_s_barrier();
    __builtin_amdgcn_sched_barrier(0);
    int t = 0;
    for (; t <= KT - 6; t += 2) {
      stage(t + 3);
      stage(t + 4);
      compute(t, acc);
      compute(t + 1, acc);
      waitcnt_vm<L>();  // tiles t+2,t+3 landed; t+4 may fly
      __builtin_amdgcn_s_barrier();
      __builtin_amdgcn_sched_barrier(0);
    }
    // t == KT-4; staged through KT-2
    stage(KT - 1);
    waitcnt_vm<0>();
    __builtin_amdgcn_s_barrier();
    compute(KT - 4, acc);
    compute(KT - 3, acc);
    compute(KT - 2, acc);
    compute(KT - 1, acc);
  }

#pragma unroll
  for (int m = 0; m < FM; ++m) {
    const int r0 = bm * BM + wr * (BM / WM) + m * 16 + lq * 4;
#pragma unroll
    for (int n = 0; n < FN; ++n) {
      const int c1 = bn * BN + wc * (BN / WN) + n * 16 + l15;
#pragma unroll
      for (int j = 0; j < 4; ++j) epi(r0 + j, c1, acc[m][n][j]);
    }
  }
}

// ================= fused gate+up GEMM, B-in-registers: act = silu(A*Bg^T)*(A*Bu^T) ====
// LDS-traffic split: only A transits LDS (RING=4 x 16KB = 64KB); B (gate & up)
// fragments load global->registers per wave (compiler-tracked vmcnt). Wave grid 2x4:
// wave owns 128 rows x 32 cols of EACH matrix (FM=8, FN=2) -> B L2 amplification 2x.
// Per K-step per block: LDS = 64KB read + 16KB write (~940cyc), VMEM = 48KB L2
// (~860cyc), MFMA ~310cyc -> pipes overlap, ~2x below the old 128KB-LDS path.
// Sync ledger: per iter issue B(t) THEN A(t+2). Compiler's wait before B(t)-use
// (vmcnt<=2) in-order-retires A(t+1) => A(t) landed before iter-t barrier for t>=1;
// uniform waitcnt vmcnt(8) before barrier (no-op steady-state, outstanding =
// A(t+1):2 + B(t):4 + A(t+2):2 = 8) covers the t=0 prologue. Slot reuse: stageA(t+2)
// writes slot (t+2)&3 = (t-2)&3, whose readers finished before iter t-1's barrier.
__global__ __launch_bounds__(512, 2)
void gemm_gateup(const bf16* __restrict__ A, const bf16* __restrict__ Bg,
                 const bf16* __restrict__ Bu, bf16* __restrict__ act) {
  constexpr int BM = 256;
  constexpr int SLOTA = BM * 64;                 // 16 KB per K-step A tile
  __shared__ __align__(16) char lds[4 * SLOTA];  // 64 KB ring

  const int tid = threadIdx.x;
  const int lane = tid & 63;
  const int wid = tid >> 6;
  const int l15 = lane & 15, lq = lane >> 4;
  const int wr = wid >> 2, wc = wid & 3;         // 2 x 4 wave grid

  const int nwg = gridDim.x;                     // 1024
  const int xcd = blockIdx.x & 7, loc = blockIdx.x >> 3;
  const int wg = xcd * (nwg >> 3) + loc;
  const int GM = 16, GN = nwg / GM;
  const int per = 8 * GN;
  const int gg = wg / per, r = wg % per;
  const int bm = gg * 8 + (r & 7);
  const int bn = r >> 3;

  const bf16* Abase = A + (int64_t)bm * BM * cD;

  // A staging: pre-swizzled global source -> linear LDS chunks (2 calls/thread)
  const bf16* srcA[2];
  int dstA[2];
#pragma unroll
  for (int c2 = 0; c2 < 2; ++c2) {
    const int chunk = c2 * 512 + tid;
    const int row = chunk >> 2, pc = chunk & 3;
    const int lc = pc ^ ((row >> 1) & 3);
    srcA[c2] = Abase + (int64_t)row * cD + lc * 8;
    dstA[c2] = chunk * 16;
  }

  // per-wave B fragment base pointers (frag n at +n*16 rows = const offset)
  const int rk0 = bn * 128 + wc * 32 + l15;
  const bf16* pG = Bg + (int64_t)rk0 * cD + lq * 8;
  const bf16* pU = Bu + (int64_t)rk0 * cD + lq * 8;

  // A fragment read offsets (swizzled), rows wr*128 + m*16 + l15
  int offA[8];
#pragma unroll
  for (int m = 0; m < 8; ++m) {
    const int row = wr * 128 + m * 16 + l15;
    offA[m] = row * 64 + (lq ^ ((row >> 1) & 3)) * 16;
  }

  const int KT = cD >> 5;  // 64
  auto stageA = [&](int t) {
    char* sb = lds + (size_t)(t & 3) * SLOTA;
    load_lds16(srcA[0] + t * 32, sb + dstA[0]);
    load_lds16(srcA[1] + t * 32, sb + dstA[1]);
  };

  f32x4 accg[8][2] = {}, accu[8][2] = {};

  stageA(0);
  stageA(1);
  for (int t = 0; t < KT; ++t) {
    // B fragment loads FIRST (issue order = implicit vmcnt ledger)
    bf16x8 gfr0 = *(const bf16x8*)(pG + t * 32);
    bf16x8 gfr1 = *(const bf16x8*)(pG + t * 32 + 16 * cD);
    bf16x8 ufr0 = *(const bf16x8*)(pU + t * 32);
    bf16x8 ufr1 = *(const bf16x8*)(pU + t * 32 + 16 * cD);
    asm volatile("" ::: "memory");
    if (t + 2 < KT) stageA(t + 2);
    asm volatile("" ::: "memory");
    waitcnt_vm<8>();  // no-op in steady state; retires A(0) before first barrier
    __builtin_amdgcn_s_barrier();
    asm volatile("" ::: "memory");
    const char* sb = lds + (size_t)(t & 3) * SLOTA;
    bf16x8 av[8];
#pragma unroll
    for (int m = 0; m < 8; ++m) av[m] = *(const bf16x8*)(sb + offA[m]);
    __builtin_amdgcn_s_setprio(1);
#pragma unroll
    for (int m = 0; m < 8; ++m) {
      accg[m][0] = __builtin_amdgcn_mfma_f32_16x16x32_bf16(av[m], gfr0, accg[m][0], 0, 0, 0);
      accg[m][1] = __builtin_amdgcn_mfma_f32_16x16x32_bf16(av[m], gfr1, accg[m][1], 0, 0, 0);
      accu[m][0] = __builtin_amdgcn_mfma_f32_16x16x32_bf16(av[m], ufr0, accu[m][0], 0, 0, 0);
      accu[m][1] = __builtin_amdgcn_mfma_f32_16x16x32_bf16(av[m], ufr1, accu[m][1], 0, 0, 0);
    }
    __builtin_amdgcn_s_setprio(0);
  }

#pragma unroll
  for (int m = 0; m < 8; ++m) {
    const int r0 = bm * BM + wr * 128 + m * 16 + lq * 4;
#pragma unroll
    for (int n = 0; n < 2; ++n) {
      const int c1 = bn * 128 + wc * 32 + n * 16 + l15;
#pragma unroll
      for (int j = 0; j < 4; ++j) {
        float gv = accg[m][n][j];
        float s = gv / (1.f + __expf(-gv));
        act[(int64_t)(r0 + j) * cFF + c1] = (bf16)(s * accu[m][n][j]);
      }
    }
  }
}

// ---------------- epilogues ----------------
struct EpiQKV {
  bf16* out; const float* bias;
  __device__ void operator()(int r, int c, float v) const {
    out[(int64_t)r * QKVW + c] = (bf16)(v + bias[c]);
  }
};
struct EpiOProj {
  float* x; const float* hidden; const int* topk;
  __device__ void operator()(int r, int c, float v) const {
    int b = r >> 10;
    int t = topk[r];
    x[(int64_t)r * cD + c] = v + hidden[((int64_t)b * cT + t) * cD + c];
  }
};
struct EpiDown {  // x2 = x + acc; upd = sel + (x2-sel)*gate; scatter to d_out
  float* out; const float* x; const float* hidden; const int* topk; const float* gating;
  __device__ void operator()(int r, int c, float v) const {
    int b = r >> 10;
    int t = topk[r];
    float x2 = v + x[(int64_t)r * cD + c];
    int64_t ho = ((int64_t)b * cT + t) * cD + c;
    float sel = hidden[ho];
    out[ho] = sel + (x2 - sel) * gating[r];
  }
};

// ================= fused flash attention =================
// grid (16 qtiles of 64 rows, 16 heads, 4 batches), 256 thr = 4 waves.
// Each wave owns 16 FULL rows x all 128 kv-cols; shfl_xor over l15 = exact row reduce.
// LDS: sK 32K (Q staged here first) | sP 16K | sV 32K = 80 KB -> 2 blocks/CU.
// All LDS tiles XOR-swizzled (16B chunk ^ row&15) via pre-swizzled global src.
__global__ __launch_bounds__(256, 2) void flash_attn(const bf16* __restrict__ qkv,
                                                     const bf16* __restrict__ vt,
                                                     bf16* __restrict__ outb) {
  constexpr int QB = 64, KVB = 128;
  __shared__ __align__(16) char lds[81920];
  char* sK = lds;            // 32 KB (also Q staging)
  char* sP = lds + 32768;    // 16 KB
  char* sV = lds + 49152;    // 32 KB

  const int qt = blockIdx.x, h = blockIdx.y, b = blockIdx.z;
  const int kvh = h >> 2;
  const int qlo = qt * QB;
  const int tid = threadIdx.x, lane = tid & 63, wid = tid >> 6;
  const int l15 = lane & 15, lq = lane >> 4;
  const int wid16 = wid * 16;  // this wave's 16-row block

  const bf16* qbase = qkv + (int64_t)(b * cK + qlo) * QKVW + h * cHD;
  const bf16* kbase = qkv + (int64_t)(b * cK) * QKVW + cH * cHD + kvh * cHD;
  const bf16* vtbase = vt + (int64_t)(b * cKVH + kvh) * cHD * cK;

  // ---- stage Q (64 rows x 256B) into sK region, read frags to regs ----
#pragma unroll
  for (int c2 = 0; c2 < 4; ++c2) {
    int chunk = c2 * 256 + tid;
    int row = chunk >> 4, c16 = chunk & 15;
    load_lds16(qbase + (int64_t)row * QKVW + (c16 ^ (row & 15)) * 8, sK + chunk * 16);
  }
  __syncthreads();
  bf16x8 qf[4];
  {
    const int row = wid16 + l15;
#pragma unroll
    for (int kt = 0; kt < 4; ++kt)
      qf[kt] = *(const bf16x8*)(sK + row * 256 + (((kt * 4 + lq) ^ (row & 15)) * 16));
  }
  __syncthreads();  // all Q reads complete before K staging overwrites sK

  f32x4 oacc[8] = {};
  float m_run[4], l_run[4];
#pragma unroll
  for (int j = 0; j < 4; ++j) { m_run[j] = -3.0e38f; l_run[j] = 0.f; }

  const int jmax = (qlo + QB - 1) >> 7;
  const float sl2e = 0.08838834764831845f * 1.44269504088896f;  // scale * log2(e)

  for (int jj = 0; jj <= jmax; ++jj) {
    // stage K tile (128 rows x 256B) and Vt tile (128 d-rows x 256B)
#pragma unroll
    for (int c2 = 0; c2 < 8; ++c2) {
      int chunk = c2 * 256 + tid;
      int row = chunk >> 4, c16 = chunk & 15;
      int cs = (c16 ^ (row & 15)) * 8;
      load_lds16(kbase + (int64_t)(jj * KVB + row) * QKVW + cs, sK + chunk * 16);
      load_lds16(vtbase + (int64_t)row * cK + jj * KVB + cs, sV + chunk * 16);
    }
    __syncthreads();

    // S = Q K^T : rows = this wave's 16 q-rows, cols = all 128 kv of this tile
    f32x4 sacc[8] = {};
#pragma unroll
    for (int kt = 0; kt < 4; ++kt) {
      bf16x8 bv[8];
#pragma unroll
      for (int n = 0; n < 8; ++n) {
        int rk = n * 16 + l15;
        bv[n] = *(const bf16x8*)(sK + rk * 256 + (((kt * 4 + lq) ^ (rk & 15)) * 16));
      }
#pragma unroll
      for (int n = 0; n < 8; ++n)
        sacc[n] = __builtin_amdgcn_mfma_f32_16x16x32_bf16(qf[kt], bv[n], sacc[n], 0, 0, 0);
    }

    // causal mask on diagonal tile
    if (jj == jmax) {
#pragma unroll
      for (int n = 0; n < 8; ++n)
#pragma unroll
        for (int j = 0; j < 4; ++j) {
          int qrow = qlo + wid16 + lq * 4 + j;
          int kcol = jj * KVB + n * 16 + l15;
          if (kcol > qrow) sacc[n][j] = -3.0e38f;
        }
    }

    // online softmax: lane owns rows (lq*4+j); full row = 8 n-frags x 16 l15 lanes
#pragma unroll
    for (int j = 0; j < 4; ++j) {
      float mx = sacc[0][j];
#pragma unroll
      for (int n = 1; n < 8; ++n) mx = fmaxf(mx, sacc[n][j]);
#pragma unroll
      for (int off = 1; off < 16; off <<= 1) mx = fmaxf(mx, __shfl_xor(mx, off, 64));
      float mnew = fmaxf(m_run[j], mx);
      float corr = exp2f((m_run[j] - mnew) * sl2e);
      m_run[j] = mnew;
      float ps = 0.f;
#pragma unroll
      for (int n = 0; n < 8; ++n) {
        float p = exp2f((sacc[n][j] - mnew) * sl2e);
        sacc[n][j] = p;
        ps += p;
      }
#pragma unroll
      for (int off = 1; off < 16; off <<= 1) ps += __shfl_xor(ps, off, 64);
      l_run[j] = l_run[j] * corr + ps;
#pragma unroll
      for (int n = 0; n < 8; ++n) oacc[n][j] *= corr;
    }

    // P -> LDS (bf16, swizzled); same wave writes and reads its own 16 rows
#pragma unroll
    for (int n = 0; n < 8; ++n)
#pragma unroll
      for (int j = 0; j < 4; ++j) {
        int row = wid16 + lq * 4 + j;
        int col = n * 16 + l15;
        int c16 = (col >> 3) ^ (row & 15);
        *(bf16*)(sP + row * 256 + c16 * 16 + (col & 7) * 2) = (bf16)sacc[n][j];
      }
    __syncthreads();

    // O += P @ Vt^T  (A = P own rows, B = Vt d-rows)
#pragma unroll
    for (int kt = 0; kt < 4; ++kt) {
      const int prow = wid16 + l15;
      bf16x8 av = *(const bf16x8*)(sP + prow * 256 + (((kt * 4 + lq) ^ (prow & 15)) * 16));
      bf16x8 bv[8];
#pragma unroll
      for (int n = 0; n < 8; ++n) {
        int rd = n * 16 + l15;
        bv[n] = *(const bf16x8*)(sV + rd * 256 + (((kt * 4 + lq) ^ (rd & 15)) * 16));
      }
#pragma unroll
      for (int n = 0; n < 8; ++n)
        oacc[n] = __builtin_amdgcn_mfma_f32_16x16x32_bf16(av, bv[n], oacc[n], 0, 0, 0);
    }
    __syncthreads();  // PV reads of sP/sV done before next stage overwrites
  }

  // O / l -> attnout
#pragma unroll
  for (int j = 0; j < 4; ++j) {
    int row = qlo + wid16 + lq * 4 + j;
    float inv = 1.f / l_run[j];
#pragma unroll
    for (int n = 0; n < 8; ++n) {
      int col = h * cHD + n * 16 + l15;
      outb[((int64_t)b * cK + row) * cD + col] = (bf16)(oacc[n][j] * inv);
    }
  }
}

// ---------------- elementwise / staging kernels ----------------
// copy only UNSELECTED rows (selected rows are fully written by EpiDown's scatter)
__global__ void copy_skip(const float4* __restrict__ s, float4* __restrict__ d,
                          const unsigned char* __restrict__ flags, int64_t n) {
  int64_t i = (int64_t)blockIdx.x * blockDim.x + threadIdx.x;
  const int64_t st = (int64_t)gridDim.x * blockDim.x;
  for (; i < n; i += st) {
    int row = (int)(i >> 9);  // 512 float4 per 2048-float row
    if (!flags[row]) d[i] = s[i];
  }
}

__global__ void build_flags(const int* __restrict__ topk, unsigned char* __restrict__ flags) {
  int r = blockIdx.x * 256 + threadIdx.x;
  if (r < cM) flags[(r >> 10) * cT + topk[r]] = 1;
}

// fp32 (R,C) -> bf16 (C,R) with column offset into a concat buffer
__global__ void wconv(const float* __restrict__ src, bf16* __restrict__ dst,
                      int R, int C, int coff, int ldd) {
  __shared__ float t[32][33];
  const int c0 = blockIdx.x * 32, r0 = blockIdx.y * 32;
  for (int rr = threadIdx.y; rr < 32; rr += 8)
    t[rr][threadIdx.x] = src[(int64_t)(r0 + rr) * C + c0 + threadIdx.x];
  __syncthreads();
  for (int rr = threadIdx.y; rr < 32; rr += 8)
    dst[(int64_t)(c0 + rr + coff) * ldd + r0 + threadIdx.x] = (bf16)t[threadIdx.x][rr];
}

__global__ void biascat(const float* __restrict__ bq, const float* __restrict__ bk,
                        const float* __restrict__ bv, float* __restrict__ o) {
  int i = blockIdx.x * 256 + threadIdx.x;
  if (i < QKVW) o[i] = (i < 2048) ? bq[i] : (i < 2560 ? bk[i - 2048] : bv[i - 2560]);
}

// gather (topk!=null) or direct rows (topk==null) + RMSNorm -> bf16
__global__ void rmsnorm_rows(const float* __restrict__ base, const int* __restrict__ topk,
                             const float* __restrict__ w, bf16* __restrict__ out) {
  const int r = blockIdx.x;
  const float* src;
  if (topk) {
    int t = topk[r];
    src = base + ((int64_t)(r >> 10) * cT + t) * cD;
  } else {
    src = base + (int64_t)r * cD;
  }
  const int tid = threadIdx.x;
  const float4* s4 = (const float4*)src;
  float4 a = s4[tid * 2], b = s4[tid * 2 + 1];
  float ss = a.x * a.x + a.y * a.y + a.z * a.z + a.w * a.w +
             b.x * b.x + b.y * b.y + b.z * b.z + b.w * b.w;
  float tot = blk_reduce<0>(ss);
  float sc = rsqrtf(tot * (1.f / cD) + 1e-6f);
  bf16* o = out + (int64_t)r * cD;
  const int d0 = tid * 8;
  o[d0 + 0] = (bf16)(a.x * sc * w[d0 + 0]);
  o[d0 + 1] = (bf16)(a.y * sc * w[d0 + 1]);
  o[d0 + 2] = (bf16)(a.z * sc * w[d0 + 2]);
  o[d0 + 3] = (bf16)(a.w * sc * w[d0 + 3]);
  o[d0 + 4] = (bf16)(b.x * sc * w[d0 + 4]);
  o[d0 + 5] = (bf16)(b.y * sc * w[d0 + 5]);
  o[d0 + 6] = (bf16)(b.z * sc * w[d0 + 6]);
  o[d0 + 7] = (bf16)(b.w * sc * w[d0 + 7]);
}

__global__ void rope_kernel(bf16* __restrict__ qkv, const float* __restrict__ cosb,
                            const float* __restrict__ sinb, const int* __restrict__ topk) {
  const int r = blockIdx.x;  // b*K + k
  const int b = r >> 10;
  const int t = topk[r];
  const float* cr = cosb + ((int64_t)b * cT + t) * cHD;
  const float* sr = sinb + ((int64_t)b * cT + t) * cHD;
  bf16* rowq = qkv + (int64_t)r * QKVW;
  for (int p = threadIdx.x; p < (cH + cKVH) * 64; p += 256) {
    int hh = p >> 6, d = p & 63;
    bf16* base = (hh < cH) ? (rowq + hh * cHD) : (rowq + cH * cHD + (hh - cH) * cHD);
    float x1 = (float)base[d], x2 = (float)base[d + 64];
    float c1 = cr[d], s1 = sr[d], c2 = cr[d + 64], s2 = sr[d + 64];
    base[d] = (bf16)(x1 * c1 - x2 * s1);
    base[d + 64] = (bf16)(x2 * c2 + x1 * s2);
  }
}

// v-part of qkv -> Vt (B,KVH,HD,K) bf16
__global__ void vtrans(const bf16* __restrict__ qkv, bf16* __restrict__ Vt) {
  __shared__ bf16 t[32][33];
  const int bz = blockIdx.z, b = bz >> 2, kv = bz & 3;
  const int k0 = blockIdx.x * 32, d0 = blockIdx.y * 32;
  for (int rr = threadIdx.y; rr < 32; rr += 8)
    t[rr][threadIdx.x] =
        qkv[(int64_t)(b * cK + k0 + rr) * QKVW + cH * cHD + cKVH * cHD + kv * cHD + d0 + threadIdx.x];
  __syncthreads();
  for (int rr = threadIdx.y; rr < 32; rr += 8)
    Vt[((int64_t)(b * cKVH + kv) * cHD + d0 + rr) * cK + k0 + threadIdx.x] = t[threadIdx.x][rr];
}

}  // namespace

extern "C" void kernel_launch(void* const* d_in, const int* in_sizes, int n_in,
                              void* d_out, int out_size, void* d_ws, size_t ws_size,
                              hipStream_t stream) {
  const float* hidden = (const float*)d_in[0];
  const int* topk = (const int*)d_in[1];
  const float* gating = (const float*)d_in[2];
  const float* cosb = (const float*)d_in[3];
  const float* sinb = (const float*)d_in[4];
  const float* Wq = (const float*)d_in[5];
  const float* bq = (const float*)d_in[6];
  const float* Wk = (const float*)d_in[7];
  const float* bk = (const float*)d_in[8];
  const float* Wv = (const float*)d_in[9];
  const float* bv = (const float*)d_in[10];
  const float* Wo = (const float*)d_in[11];
  const float* wg = (const float*)d_in[12];
  const float* wu = (const float*)d_in[13];
  const float* wd = (const float*)d_in[14];
  const float* ln1 = (const float*)d_in[15];
  const float* ln2 = (const float*)d_in[16];
  float* out = (float*)d_out;
  (void)in_sizes; (void)n_in; (void)out_size; (void)ws_size;

  char* ws = (char*)d_ws;
  size_t off = 0;
  auto alloc = [&](size_t bytes) {
    char* p = ws + off;
    off += (bytes + 255) & ~(size_t)255;
    return p;
  };
  bf16* wt_qkv = (bf16*)alloc((size_t)QKVW * cD * 2);
  bf16* wt_o = (bf16*)alloc((size_t)cD * cD * 2);
  bf16* wt_g = (bf16*)alloc((size_t)cFF * cD * 2);
  bf16* wt_u = (bf16*)alloc((size_t)cFF * cD * 2);
  bf16* wt_d = (bf16*)alloc((size_t)cD * cFF * 2);
  float* bias_cat = (float*)alloc((size_t)QKVW * 4);
  bf16* hbuf = (bf16*)alloc((size_t)cM * cD * 2);
  bf16* qkv = (bf16*)alloc((size_t)cM * QKVW * 2);
  bf16* vt = (bf16*)alloc((size_t)cB * cKVH * cHD * cK * 2);
  bf16* attnout = (bf16*)alloc((size_t)cM * cD * 2);
  float* xbuf = (float*)alloc((size_t)cM * cD * 4);
  bf16* actbuf = (bf16*)alloc((size_t)cM * cFF * 2);
  unsigned char* flags = (unsigned char*)alloc((size_t)cB * cT);

  // flags = selected-row mask; copy only unselected rows (EpiDown writes selected)
  hipMemsetAsync(flags, 0, (size_t)cB * cT, stream);
  build_flags<<<cM / 256, 256, 0, stream>>>(topk, flags);
  copy_skip<<<2048, 256, 0, stream>>>((const float4*)hidden, (float4*)out, flags,
                                      (int64_t)cB * cT * cD / 4);

  const dim3 tb(32, 8);
  wconv<<<dim3(cD / 32, cD / 32), tb, 0, stream>>>(Wq, wt_qkv, cD, cD, 0, cD);
  wconv<<<dim3(512 / 32, cD / 32), tb, 0, stream>>>(Wk, wt_qkv, cD, 512, 2048, cD);
  wconv<<<dim3(512 / 32, cD / 32), tb, 0, stream>>>(Wv, wt_qkv, cD, 512, 2560, cD);
  wconv<<<dim3(cD / 32, cD / 32), tb, 0, stream>>>(Wo, wt_o, cD, cD, 0, cD);
  wconv<<<dim3(cFF / 32, cD / 32), tb, 0, stream>>>(wg, wt_g, cD, cFF, 0, cD);
  wconv<<<dim3(cFF / 32, cD / 32), tb, 0, stream>>>(wu, wt_u, cD, cFF, 0, cD);
  wconv<<<dim3(cD / 32, cFF / 32), tb, 0, stream>>>(wd, wt_d, cFF, cD, 0, cFF);
  biascat<<<(QKVW + 255) / 256, 256, 0, stream>>>(bq, bk, bv, bias_cat);

  // gather + rmsnorm1
  rmsnorm_rows<<<cM, 256, 0, stream>>>(hidden, topk, ln1, hbuf);
  // qkv projection (+bias)   [pair-mode pipeline]
  gemm256<256, 2, 4, 5, 2, EpiQKV><<<16 * (QKVW / 256), 512, 0, stream>>>(
      hbuf, cD, wt_qkv, cD, cD, 16, EpiQKV{qkv, bias_cat});
  rope_kernel<<<cM, 256, 0, stream>>>(qkv, cosb, sinb, topk);
  vtrans<<<dim3(cK / 32, cHD / 32, cB * cKVH), tb, 0, stream>>>(qkv, vt);

  // fused flash attention (replaces S-GEMM + softmax + PV)
  flash_attn<<<dim3(cK / 64, cH, cB), 256, 0, stream>>>(qkv, vt, attnout);

  // o-proj + gathered residual -> x (fp32)   [pair-mode pipeline]
  gemm256<128, 4, 2, 5, 2, EpiOProj><<<16 * (cD / 128), 512, 0, stream>>>(
      attnout, cD, wt_o, cD, cD, 16, EpiOProj{xbuf, hidden, topk});
  // rmsnorm2
  rmsnorm_rows<<<cM, 256, 0, stream>>>(xbuf, nullptr, ln2, hbuf);
  // fused gate+up -> act = silu(gate)*up   [B-in-registers pipeline]
  gemm_gateup<<<16 * (cFF / 128), 512, 0, stream>>>(hbuf, wt_g, wt_u, actbuf);
  // down + residual + gating + scatter into d_out   [pair-mode pipeline]
  gemm256<128, 4, 2, 5, 2, EpiDown><<<16 * (cD / 128), 512, 0, stream>>>(
      actbuf, cFF, wt_d, cFF, cFF, 16, EpiDown{out, xbuf, hidden, topk, gating});
}

// Round 12
// 855.939 us; speedup vs baseline: 1.0781x; 1.0781x over previous
//
#include <hip/hip_runtime.h>
#include <stdint.h>

typedef __bf16 bf16;
typedef __attribute__((ext_vector_type(8))) __bf16 bf16x8;
typedef __attribute__((ext_vector_type(4))) float f32x4;

namespace {

constexpr int cB = 4, cT = 4096, cD = 2048, cK = 1024, cH = 16, cKVH = 4, cHD = 128, cFF = 8192;
constexpr int cM = cB * cK;                 // 4096 gathered rows
constexpr int QKVW = cH * cHD + 2 * cKVH * cHD; // 3072

__device__ __forceinline__ void load_lds16(const void* g, void* l) {
  __builtin_amdgcn_global_load_lds((const __attribute__((address_space(1))) void*)g,
                                   (__attribute__((address_space(3))) void*)l, 16, 0, 0);
}

template <int N>
__device__ __forceinline__ void waitcnt_vm() {
  if constexpr (N == 0) asm volatile("s_waitcnt vmcnt(0)" ::: "memory");
  else if constexpr (N == 3) asm volatile("s_waitcnt vmcnt(3)" ::: "memory");
  else if constexpr (N == 4) asm volatile("s_waitcnt vmcnt(4)" ::: "memory");
  else if constexpr (N == 6) asm volatile("s_waitcnt vmcnt(6)" ::: "memory");
  else if constexpr (N == 8) asm volatile("s_waitcnt vmcnt(8)" ::: "memory");
  else if constexpr (N == 9) asm volatile("s_waitcnt vmcnt(9)" ::: "memory");
  else if constexpr (N == 12) asm volatile("s_waitcnt vmcnt(12)" ::: "memory");
  else static_assert(N == 0, "unsupported vmcnt literal");
}

// ---------------- block reduce (256 threads = 4 waves) ----------------
template <int OP>  // 0 = sum, 1 = max
__device__ __forceinline__ float blk_reduce(float v) {
  __shared__ float sm[5];
  const int tid = threadIdx.x, lane = tid & 63, wid = tid >> 6;
#pragma unroll
  for (int o = 32; o; o >>= 1) {
    float o2 = __shfl_down(v, o, 64);
    v = OP ? fmaxf(v, o2) : v + o2;
  }
  if (lane == 0) sm[wid] = v;
  __syncthreads();
  if (tid == 0) {
    float r = sm[0];
#pragma unroll
    for (int i = 1; i < 4; ++i) r = OP ? fmaxf(r, sm[i]) : r + sm[i];
    sm[4] = r;
  }
  __syncthreads();
  float r = sm[4];
  __syncthreads();
  return r;
}

// ================= deep-pipelined 256-row MFMA GEMM: C = A * B^T =================
// A: M x Kd row-major (lda), B: N x Kd row-major (ldb). BM=256, BK=32.
// 8 waves (512 thr), WM x WN wave grid, RING-slot LDS ring, counted vmcnt, raw
// barriers, XOR-swizzled LDS (pre-swizzled global src + swizzled ds_read_b128).
// UNROLL=1: prologue D=RING-1 tiles, main waits (D-1)*L; tail = vmcnt(0) + D computes.
// UNROLL=2 (RING=5): two K-steps per barrier; bridge = stage(KT-1), vmcnt(0), 4 computes.
template <int BN, int WM, int WN, int RING, int UNROLL, class Epi>
__global__ __launch_bounds__(512, 2)
void gemm256(const bf16* __restrict__ A, int lda,
             const bf16* __restrict__ Bm, int ldb,
             int Kd, int GM, Epi epi) {
  constexpr int BM = 256;
  constexpr int FM = BM / WM / 16;
  constexpr int FN = BN / WN / 16;
  constexpr int ACALLS = 2;          // 256 rows * 64B / (512 thr * 16B)
  constexpr int BCALLS = BN / 128;
  constexpr int L = ACALLS + BCALLS; // vmem instrs per K-tile per thread
  constexpr int D = RING - 1;        // UNROLL=1 prefetch depth
  constexpr int SLOTA = BM * 64;     // bytes per A K-tile (BK=32 -> 64B rows)
  constexpr int SLOTB = BN * 64;
  constexpr int SLOT = SLOTA + SLOTB;
  __shared__ __align__(16) char lds[RING * SLOT];

  const int tid = threadIdx.x;
  const int lane = tid & 63;
  const int wid = tid >> 6;
  const int l15 = lane & 15, lq = lane >> 4;
  const int wr = wid / WN, wc = wid % WN;

  // per-XCD contiguous chunk (nwg % 8 == 0 for all our launches)
  const int nwg = gridDim.x;
  const int xcd = blockIdx.x & 7, loc = blockIdx.x >> 3;
  const int wg = xcd * (nwg >> 3) + loc;
  // grouped mapping: 8 bm fastest, then bn
  const int GN = nwg / GM;
  const int per = 8 * GN;
  const int g = wg / per, r = wg % per;
  const int bm = g * 8 + (r & 7);
  const int bn = r >> 3;

  const bf16* Abase = A + (int64_t)bm * BM * lda;
  const bf16* Bbase = Bm + (int64_t)bn * BN * ldb;

  // staging: LDS linear chunk -> pre-swizzled global source
  const bf16* srcA[ACALLS];
  int dstA[ACALLS];
#pragma unroll
  for (int c2 = 0; c2 < ACALLS; ++c2) {
    const int chunk = c2 * 512 + tid;
    const int row = chunk >> 2, pc = chunk & 3;
    const int lc = pc ^ ((row >> 1) & 3);
    srcA[c2] = Abase + (int64_t)row * lda + lc * 8;
    dstA[c2] = chunk * 16;
  }
  const bf16* srcB[BCALLS];
  int dstB[BCALLS];
#pragma unroll
  for (int c2 = 0; c2 < BCALLS; ++c2) {
    const int chunk = c2 * 512 + tid;
    const int row = chunk >> 2, pc = chunk & 3;
    const int lc = pc ^ ((row >> 1) & 3);
    srcB[c2] = Bbase + (int64_t)row * ldb + lc * 8;
    dstB[c2] = chunk * 16;
  }

  // fragment read offsets (swizzled)
  int offA[FM], offB[FN];
#pragma unroll
  for (int m = 0; m < FM; ++m) {
    const int row = wr * (BM / WM) + m * 16 + l15;
    offA[m] = row * 64 + (lq ^ ((row >> 1) & 3)) * 16;
  }
#pragma unroll
  for (int n = 0; n < FN; ++n) {
    const int row = wc * (BN / WN) + n * 16 + l15;
    offB[n] = SLOTA + row * 64 + (lq ^ ((row >> 1) & 3)) * 16;
  }

  const int KT = Kd >> 5;
  auto stage = [&](int t) {
    char* sb = lds + (size_t)(t % RING) * SLOT;
#pragma unroll
    for (int c2 = 0; c2 < ACALLS; ++c2)
      load_lds16(srcA[c2] + t * 32, sb + dstA[c2]);
#pragma unroll
    for (int c2 = 0; c2 < BCALLS; ++c2)
      load_lds16(srcB[c2] + t * 32, sb + SLOTA + dstB[c2]);
  };
  auto compute = [&](int t, f32x4 (&acc)[FM][FN]) {
    const char* sb = lds + (size_t)(t % RING) * SLOT;
    bf16x8 av[FM], bv[FN];
#pragma unroll
    for (int m = 0; m < FM; ++m) av[m] = *(const bf16x8*)(sb + offA[m]);
#pragma unroll
    for (int n = 0; n < FN; ++n) bv[n] = *(const bf16x8*)(sb + offB[n]);
    __builtin_amdgcn_s_setprio(1);
#pragma unroll
    for (int m = 0; m < FM; ++m)
#pragma unroll
      for (int n = 0; n < FN; ++n)
        acc[m][n] = __builtin_amdgcn_mfma_f32_16x16x32_bf16(av[m], bv[n], acc[m][n], 0, 0, 0);
    __builtin_amdgcn_s_setprio(0);
  };

  f32x4 acc[FM][FN] = {};

  if constexpr (UNROLL == 1) {
#pragma unroll
    for (int i = 0; i < D; ++i) stage(i);
    waitcnt_vm<(D - 1) * L>();
    __builtin_amdgcn_s_barrier();
    __builtin_amdgcn_sched_barrier(0);
    for (int t = 0; t < KT - D; ++t) {
      stage(t + D);
      compute(t, acc);
      waitcnt_vm<(D - 1) * L>();
      __builtin_amdgcn_s_barrier();
      __builtin_amdgcn_sched_barrier(0);
    }
    // tail: all remaining tiles staged; one full drain, then straight computes
    waitcnt_vm<0>();
    __builtin_amdgcn_s_barrier();
    for (int t = KT - D; t < KT; ++t) compute(t, acc);
  } else {
    static_assert(RING == 5 && UNROLL == 2, "pair mode is RING=5");
#pragma unroll
    for (int i = 0; i < 3; ++i) stage(i);
    waitcnt_vm<L>();  // tiles 0,1 landed (tile 2 may be in flight)
    __builtin_amdgcn_s_barrier();
    __builtin_amdgcn_sched_barrier(0);
    int t = 0;
    for (; t <= KT - 6; t += 2) {
      stage(t + 3);
      stage(t + 4);
      compute(t, acc);
      compute(t + 1, acc);
      waitcnt_vm<L>();  // tiles t+2,t+3 landed; t+4 may fly
      __builtin_amdgcn_s_barrier();
      __builtin_amdgcn_sched_barrier(0);
    }
    // t == KT-4; staged through KT-2
    stage(KT - 1);
    waitcnt_vm<0>();
    __builtin_amdgcn_s_barrier();
    compute(KT - 4, acc);
    compute(KT - 3, acc);
    compute(KT - 2, acc);
    compute(KT - 1, acc);
  }

#pragma unroll
  for (int m = 0; m < FM; ++m) {
    const int r0 = bm * BM + wr * (BM / WM) + m * 16 + lq * 4;
#pragma unroll
    for (int n = 0; n < FN; ++n) {
      const int c1 = bn * BN + wc * (BN / WN) + n * 16 + l15;
#pragma unroll
      for (int j = 0; j < 4; ++j) epi(r0 + j, c1, acc[m][n][j]);
    }
  }
}

// ====== fused gate+up GEMM v3: frag-ordered B in registers, prefetched ======
// ROUND-12: round-11's B-in-reg regressed because B loads were 4KB-STRIDED (16 cache
// lines / instr, TA-serialized) and used ~100cyc after issue (L2-latency stall).
// Fix: (1) B stored FRAGMENT-ORDERED (wconv_frag): frag (nb,kc) = 64 lanes x 16B
// CONTIGUOUS -> each wave B-load = one coalesced 1KB global_load_dwordx4;
// (2) B prefetched one K-step ahead via manual unroll-2 with named reg sets.
// A in LDS ring (RING=4 x 16KB = 64KB -> 2 blocks/CU). Wave grid 2x4 (128 rows x
// 32 cols each matrix, FM=8, FN=2). Per iter per block: LDS 64KB read + 16KB DMA,
// VMEM 48KB coalesced, 256 MFMA.
// vmcnt ledger (walked per half): even half needs A(t): after it in issue order
// B(t):4,A(t+1):2,B(t+1):4,A(t+2):2 = 12 -> vmcnt(8) (over-retires B(t), free).
// odd half needs A(t+1): after it B(t+1):4,A(t+2):2,B(t+2):4,A(t+3):2 -> vmcnt(6)
// steady; TAIL (t+3>=KT): only B(KT-1):4 after it -> vmcnt(4) (else A(KT-1) never
// retired -- the round-2-class tail hole, closed by the runtime branch).
__global__ __launch_bounds__(512, 2)
void gemm_gateup(const bf16* __restrict__ A, const bf16* __restrict__ Bg,
                 const bf16* __restrict__ Bu, bf16* __restrict__ act) {
  constexpr int BM = 256;
  constexpr int SLOTA = BM * 64;                 // 16 KB per K-step A tile
  __shared__ __align__(16) char lds[4 * SLOTA];  // 64 KB ring

  const int tid = threadIdx.x;
  const int lane = tid & 63;
  const int wid = tid >> 6;
  const int l15 = lane & 15, lq = lane >> 4;
  const int wr = wid >> 2, wc = wid & 3;         // 2 x 4 wave grid

  const int nwg = gridDim.x;                     // 1024
  const int xcd = blockIdx.x & 7, loc = blockIdx.x >> 3;
  const int wg = xcd * (nwg >> 3) + loc;
  const int GM = 16, GN = nwg / GM;
  const int per = 8 * GN;
  const int gg = wg / per, r = wg % per;
  const int bm = gg * 8 + (r & 7);
  const int bn = r >> 3;

  const bf16* Abase = A + (int64_t)bm * BM * cD;

  // A staging: pre-swizzled global source -> linear LDS chunks (2 calls/thread)
  const bf16* srcA[2];
  int dstA[2];
#pragma unroll
  for (int c2 = 0; c2 < 2; ++c2) {
    const int chunk = c2 * 512 + tid;
    const int row = chunk >> 2, pc = chunk & 3;
    const int lc = pc ^ ((row >> 1) & 3);
    srcA[c2] = Abase + (int64_t)row * cD + lc * 8;
    dstA[c2] = chunk * 16;
  }

  const int KT = cD >> 5;  // 64 (even)
  // fragment-ordered B: frag (nb,kc) base = ((nb*KT + kc)*64 + lane)*8; wave loads 1KB
  const int nb0 = bn * 8 + wc * 2;   // first 16-col block of this wave
  const bf16* pG0 = Bg + ((int64_t)nb0 * KT * 64 + lane) * 8;
  const bf16* pG1 = Bg + ((int64_t)(nb0 + 1) * KT * 64 + lane) * 8;
  const bf16* pU0 = Bu + ((int64_t)nb0 * KT * 64 + lane) * 8;
  const bf16* pU1 = Bu + ((int64_t)(nb0 + 1) * KT * 64 + lane) * 8;

  // A fragment read offsets (swizzled), rows wr*128 + m*16 + l15
  int offA[8];
#pragma unroll
  for (int m = 0; m < 8; ++m) {
    const int row = wr * 128 + m * 16 + l15;
    offA[m] = row * 64 + (lq ^ ((row >> 1) & 3)) * 16;
  }

  auto stageA = [&](int t) {
    char* sb = lds + (size_t)(t & 3) * SLOTA;
    load_lds16(srcA[0] + t * 32, sb + dstA[0]);
    load_lds16(srcA[1] + t * 32, sb + dstA[1]);
  };

  f32x4 accg[8][2] = {}, accu[8][2] = {};
  bf16x8 gA0, gA1, uA0, uA1, gB0, gB1, uB0, uB1;

  auto loadB = [&](int t, bf16x8& g0, bf16x8& g1, bf16x8& u0, bf16x8& u1) {
    g0 = *(const bf16x8*)(pG0 + (int64_t)t * 512);
    g1 = *(const bf16x8*)(pG1 + (int64_t)t * 512);
    u0 = *(const bf16x8*)(pU0 + (int64_t)t * 512);
    u1 = *(const bf16x8*)(pU1 + (int64_t)t * 512);
  };
  auto mfma_step = [&](const char* sb, const bf16x8& g0, const bf16x8& g1,
                       const bf16x8& u0, const bf16x8& u1) {
    bf16x8 av[8];
#pragma unroll
    for (int m = 0; m < 8; ++m) av[m] = *(const bf16x8*)(sb + offA[m]);
    __builtin_amdgcn_s_setprio(1);
#pragma unroll
    for (int m = 0; m < 8; ++m) {
      accg[m][0] = __builtin_amdgcn_mfma_f32_16x16x32_bf16(av[m], g0, accg[m][0], 0, 0, 0);
      accg[m][1] = __builtin_amdgcn_mfma_f32_16x16x32_bf16(av[m], g1, accg[m][1], 0, 0, 0);
      accu[m][0] = __builtin_amdgcn_mfma_f32_16x16x32_bf16(av[m], u0, accu[m][0], 0, 0, 0);
      accu[m][1] = __builtin_amdgcn_mfma_f32_16x16x32_bf16(av[m], u1, accu[m][1], 0, 0, 0);
    }
    __builtin_amdgcn_s_setprio(0);
  };

  loadB(0, gA0, gA1, uA0, uA1);
  stageA(0);
  stageA(1);
  for (int t = 0; t < KT; t += 2) {
    // even half: compute t with gA set; prefetch B(t+1), A(t+2)
    loadB(t + 1, gB0, gB1, uB0, uB1);
    if (t + 2 < KT) stageA(t + 2);
    waitcnt_vm<8>();
    __builtin_amdgcn_s_barrier();
    mfma_step(lds + (size_t)(t & 3) * SLOTA, gA0, gA1, uA0, uA1);
    // odd half: compute t+1 with gB set; prefetch B(t+2), A(t+3)
    if (t + 2 < KT) loadB(t + 2, gA0, gA1, uA0, uA1);
    if (t + 3 < KT) stageA(t + 3);
    if (t + 3 < KT) waitcnt_vm<6>();
    else            waitcnt_vm<4>();  // tail: retire A(KT-1) (only B(KT-1):4 younger)
    __builtin_amdgcn_s_barrier();
    mfma_step(lds + (size_t)((t + 1) & 3) * SLOTA, gB0, gB1, uB0, uB1);
  }

#pragma unroll
  for (int m = 0; m < 8; ++m) {
    const int r0 = bm * BM + wr * 128 + m * 16 + lq * 4;
#pragma unroll
    for (int n = 0; n < 2; ++n) {
      const int c1 = bn * 128 + wc * 32 + n * 16 + l15;
#pragma unroll
      for (int j = 0; j < 4; ++j) {
        float gv = accg[m][n][j];
        float s = gv / (1.f + __expf(-gv));
        act[(int64_t)(r0 + j) * cFF + c1] = (bf16)(s * accu[m][n][j]);
      }
    }
  }
}

// ---------------- epilogues ----------------
struct EpiQKV {
  bf16* out; const float* bias;
  __device__ void operator()(int r, int c, float v) const {
    out[(int64_t)r * QKVW + c] = (bf16)(v + bias[c]);
  }
};
struct EpiOProj {
  float* x; const float* hidden; const int* topk;
  __device__ void operator()(int r, int c, float v) const {
    int b = r >> 10;
    int t = topk[r];
    x[(int64_t)r * cD + c] = v + hidden[((int64_t)b * cT + t) * cD + c];
  }
};
struct EpiDown {  // x2 = x + acc; upd = sel + (x2-sel)*gate; scatter to d_out
  float* out; const float* x; const float* hidden; const int* topk; const float* gating;
  __device__ void operator()(int r, int c, float v) const {
    int b = r >> 10;
    int t = topk[r];
    float x2 = v + x[(int64_t)r * cD + c];
    int64_t ho = ((int64_t)b * cT + t) * cD + c;
    float sel = hidden[ho];
    out[ho] = sel + (x2 - sel) * gating[r];
  }
};

// ================= fused flash attention =================
// grid (16 qtiles of 64 rows, 16 heads, 4 batches), 256 thr = 4 waves.
// Each wave owns 16 FULL rows x all 128 kv-cols; shfl_xor over l15 = exact row reduce.
// LDS: sK 32K (Q staged here first) | sP 16K | sV 32K = 80 KB -> 2 blocks/CU.
// All LDS tiles XOR-swizzled (16B chunk ^ row&15) via pre-swizzled global src.
__global__ __launch_bounds__(256, 2) void flash_attn(const bf16* __restrict__ qkv,
                                                     const bf16* __restrict__ vt,
                                                     bf16* __restrict__ outb) {
  constexpr int QB = 64, KVB = 128;
  __shared__ __align__(16) char lds[81920];
  char* sK = lds;            // 32 KB (also Q staging)
  char* sP = lds + 32768;    // 16 KB
  char* sV = lds + 49152;    // 32 KB

  const int qt = blockIdx.x, h = blockIdx.y, b = blockIdx.z;
  const int kvh = h >> 2;
  const int qlo = qt * QB;
  const int tid = threadIdx.x, lane = tid & 63, wid = tid >> 6;
  const int l15 = lane & 15, lq = lane >> 4;
  const int wid16 = wid * 16;  // this wave's 16-row block

  const bf16* qbase = qkv + (int64_t)(b * cK + qlo) * QKVW + h * cHD;
  const bf16* kbase = qkv + (int64_t)(b * cK) * QKVW + cH * cHD + kvh * cHD;
  const bf16* vtbase = vt + (int64_t)(b * cKVH + kvh) * cHD * cK;

  // ---- stage Q (64 rows x 256B) into sK region, read frags to regs ----
#pragma unroll
  for (int c2 = 0; c2 < 4; ++c2) {
    int chunk = c2 * 256 + tid;
    int row = chunk >> 4, c16 = chunk & 15;
    load_lds16(qbase + (int64_t)row * QKVW + (c16 ^ (row & 15)) * 8, sK + chunk * 16);
  }
  __syncthreads();
  bf16x8 qf[4];
  {
    const int row = wid16 + l15;
#pragma unroll
    for (int kt = 0; kt < 4; ++kt)
      qf[kt] = *(const bf16x8*)(sK + row * 256 + (((kt * 4 + lq) ^ (row & 15)) * 16));
  }
  __syncthreads();  // all Q reads complete before K staging overwrites sK

  f32x4 oacc[8] = {};
  float m_run[4], l_run[4];
#pragma unroll
  for (int j = 0; j < 4; ++j) { m_run[j] = -3.0e38f; l_run[j] = 0.f; }

  const int jmax = (qlo + QB - 1) >> 7;
  const float sl2e = 0.08838834764831845f * 1.44269504088896f;  // scale * log2(e)

  for (int jj = 0; jj <= jmax; ++jj) {
    // stage K tile (128 rows x 256B) and Vt tile (128 d-rows x 256B)
#pragma unroll
    for (int c2 = 0; c2 < 8; ++c2) {
      int chunk = c2 * 256 + tid;
      int row = chunk >> 4, c16 = chunk & 15;
      int cs = (c16 ^ (row & 15)) * 8;
      load_lds16(kbase + (int64_t)(jj * KVB + row) * QKVW + cs, sK + chunk * 16);
      load_lds16(vtbase + (int64_t)row * cK + jj * KVB + cs, sV + chunk * 16);
    }
    __syncthreads();

    // S = Q K^T : rows = this wave's 16 q-rows, cols = all 128 kv of this tile
    f32x4 sacc[8] = {};
#pragma unroll
    for (int kt = 0; kt < 4; ++kt) {
      bf16x8 bv[8];
#pragma unroll
      for (int n = 0; n < 8; ++n) {
        int rk = n * 16 + l15;
        bv[n] = *(const bf16x8*)(sK + rk * 256 + (((kt * 4 + lq) ^ (rk & 15)) * 16));
      }
#pragma unroll
      for (int n = 0; n < 8; ++n)
        sacc[n] = __builtin_amdgcn_mfma_f32_16x16x32_bf16(qf[kt], bv[n], sacc[n], 0, 0, 0);
    }

    // causal mask on diagonal tile
    if (jj == jmax) {
#pragma unroll
      for (int n = 0; n < 8; ++n)
#pragma unroll
        for (int j = 0; j < 4; ++j) {
          int qrow = qlo + wid16 + lq * 4 + j;
          int kcol = jj * KVB + n * 16 + l15;
          if (kcol > qrow) sacc[n][j] = -3.0e38f;
        }
    }

    // online softmax: lane owns rows (lq*4+j); full row = 8 n-frags x 16 l15 lanes
#pragma unroll
    for (int j = 0; j < 4; ++j) {
      float mx = sacc[0][j];
#pragma unroll
      for (int n = 1; n < 8; ++n) mx = fmaxf(mx, sacc[n][j]);
#pragma unroll
      for (int off = 1; off < 16; off <<= 1) mx = fmaxf(mx, __shfl_xor(mx, off, 64));
      float mnew = fmaxf(m_run[j], mx);
      float corr = exp2f((m_run[j] - mnew) * sl2e);
      m_run[j] = mnew;
      float ps = 0.f;
#pragma unroll
      for (int n = 0; n < 8; ++n) {
        float p = exp2f((sacc[n][j] - mnew) * sl2e);
        sacc[n][j] = p;
        ps += p;
      }
#pragma unroll
      for (int off = 1; off < 16; off <<= 1) ps += __shfl_xor(ps, off, 64);
      l_run[j] = l_run[j] * corr + ps;
#pragma unroll
      for (int n = 0; n < 8; ++n) oacc[n][j] *= corr;
    }

    // P -> LDS (bf16, swizzled); same wave writes and reads its own 16 rows
#pragma unroll
    for (int n = 0; n < 8; ++n)
#pragma unroll
      for (int j = 0; j < 4; ++j) {
        int row = wid16 + lq * 4 + j;
        int col = n * 16 + l15;
        int c16 = (col >> 3) ^ (row & 15);
        *(bf16*)(sP + row * 256 + c16 * 16 + (col & 7) * 2) = (bf16)sacc[n][j];
      }
    __syncthreads();

    // O += P @ Vt^T  (A = P own rows, B = Vt d-rows)
#pragma unroll
    for (int kt = 0; kt < 4; ++kt) {
      const int prow = wid16 + l15;
      bf16x8 av = *(const bf16x8*)(sP + prow * 256 + (((kt * 4 + lq) ^ (prow & 15)) * 16));
      bf16x8 bv[8];
#pragma unroll
      for (int n = 0; n < 8; ++n) {
        int rd = n * 16 + l15;
        bv[n] = *(const bf16x8*)(sV + rd * 256 + (((kt * 4 + lq) ^ (rd & 15)) * 16));
      }
#pragma unroll
      for (int n = 0; n < 8; ++n)
        oacc[n] = __builtin_amdgcn_mfma_f32_16x16x32_bf16(av, bv[n], oacc[n], 0, 0, 0);
    }
    __syncthreads();  // PV reads of sP/sV done before next stage overwrites
  }

  // O / l -> attnout
#pragma unroll
  for (int j = 0; j < 4; ++j) {
    int row = qlo + wid16 + lq * 4 + j;
    float inv = 1.f / l_run[j];
#pragma unroll
    for (int n = 0; n < 8; ++n) {
      int col = h * cHD + n * 16 + l15;
      outb[((int64_t)b * cK + row) * cD + col] = (bf16)(oacc[n][j] * inv);
    }
  }
}

// ---------------- elementwise / staging kernels ----------------
// copy only UNSELECTED rows (selected rows are fully written by EpiDown's scatter)
__global__ void copy_skip(const float4* __restrict__ s, float4* __restrict__ d,
                          const unsigned char* __restrict__ flags, int64_t n) {
  int64_t i = (int64_t)blockIdx.x * blockDim.x + threadIdx.x;
  const int64_t st = (int64_t)gridDim.x * blockDim.x;
  for (; i < n; i += st) {
    int row = (int)(i >> 9);  // 512 float4 per 2048-float row
    if (!flags[row]) d[i] = s[i];
  }
}

__global__ void build_flags(const int* __restrict__ topk, unsigned char* __restrict__ flags) {
  int r = blockIdx.x * 256 + threadIdx.x;
  if (r < cM) flags[(r >> 10) * cT + topk[r]] = 1;
}

// fp32 (R,C) -> bf16 (C,R) with column offset into a concat buffer
__global__ void wconv(const float* __restrict__ src, bf16* __restrict__ dst,
                      int R, int C, int coff, int ldd) {
  __shared__ float t[32][33];
  const int c0 = blockIdx.x * 32, r0 = blockIdx.y * 32;
  for (int rr = threadIdx.y; rr < 32; rr += 8)
    t[rr][threadIdx.x] = src[(int64_t)(r0 + rr) * C + c0 + threadIdx.x];
  __syncthreads();
  for (int rr = threadIdx.y; rr < 32; rr += 8)
    dst[(int64_t)(c0 + rr + coff) * ldd + r0 + threadIdx.x] = (bf16)t[threadIdx.x][rr];
}

// fp32 (K,N) row-major -> bf16 FRAGMENT-ORDERED: frag (nb,kc) at ((nb*KT+kc)*64+lane)*8;
// elem (lane = lq*16+l15, j) = src[(kc*32+lq*8+j)*N + nb*16+l15]. One thread per
// (frag,lane): writes 16B contiguous (wave = 1KB contiguous); reads coalesce in 64B runs.
__global__ void wconv_frag(const float* __restrict__ src, bf16* __restrict__ dst,
                           int N, int KT) {
  const int id = blockIdx.x * 256 + threadIdx.x;
  const int lane = id & 63;
  const int frag = id >> 6;
  const int kc = frag % KT;
  const int nb = frag / KT;
  const int l15 = lane & 15, lq = lane >> 4;
  const float* s = src + (int64_t)(kc * 32 + lq * 8) * N + nb * 16 + l15;
  bf16* o = dst + (int64_t)id * 8;
#pragma unroll
  for (int j = 0; j < 8; ++j) o[j] = (bf16)s[(int64_t)j * N];
}

__global__ void biascat(const float* __restrict__ bq, const float* __restrict__ bk,
                        const float* __restrict__ bv, float* __restrict__ o) {
  int i = blockIdx.x * 256 + threadIdx.x;
  if (i < QKVW) o[i] = (i < 2048) ? bq[i] : (i < 2560 ? bk[i - 2048] : bv[i - 2560]);
}

// gather (topk!=null) or direct rows (topk==null) + RMSNorm -> bf16
__global__ void rmsnorm_rows(const float* __restrict__ base, const int* __restrict__ topk,
                             const float* __restrict__ w, bf16* __restrict__ out) {
  const int r = blockIdx.x;
  const float* src;
  if (topk) {
    int t = topk[r];
    src = base + ((int64_t)(r >> 10) * cT + t) * cD;
  } else {
    src = base + (int64_t)r * cD;
  }
  const int tid = threadIdx.x;
  const float4* s4 = (const float4*)src;
  float4 a = s4[tid * 2], b = s4[tid * 2 + 1];
  float ss = a.x * a.x + a.y * a.y + a.z * a.z + a.w * a.w +
             b.x * b.x + b.y * b.y + b.z * b.z + b.w * b.w;
  float tot = blk_reduce<0>(ss);
  float sc = rsqrtf(tot * (1.f / cD) + 1e-6f);
  bf16* o = out + (int64_t)r * cD;
  const int d0 = tid * 8;
  o[d0 + 0] = (bf16)(a.x * sc * w[d0 + 0]);
  o[d0 + 1] = (bf16)(a.y * sc * w[d0 + 1]);
  o[d0 + 2] = (bf16)(a.z * sc * w[d0 + 2]);
  o[d0 + 3] = (bf16)(a.w * sc * w[d0 + 3]);
  o[d0 + 4] = (bf16)(b.x * sc * w[d0 + 4]);
  o[d0 + 5] = (bf16)(b.y * sc * w[d0 + 5]);
  o[d0 + 6] = (bf16)(b.z * sc * w[d0 + 6]);
  o[d0 + 7] = (bf16)(b.w * sc * w[d0 + 7]);
}

__global__ void rope_kernel(bf16* __restrict__ qkv, const float* __restrict__ cosb,
                            const float* __restrict__ sinb, const int* __restrict__ topk) {
  const int r = blockIdx.x;  // b*K + k
  const int b = r >> 10;
  const int t = topk[r];
  const float* cr = cosb + ((int64_t)b * cT + t) * cHD;
  const float* sr = sinb + ((int64_t)b * cT + t) * cHD;
  bf16* rowq = qkv + (int64_t)r * QKVW;
  for (int p = threadIdx.x; p < (cH + cKVH) * 64; p += 256) {
    int hh = p >> 6, d = p & 63;
    bf16* base = (hh < cH) ? (rowq + hh * cHD) : (rowq + cH * cHD + (hh - cH) * cHD);
    float x1 = (float)base[d], x2 = (float)base[d + 64];
    float c1 = cr[d], s1 = sr[d], c2 = cr[d + 64], s2 = sr[d + 64];
    base[d] = (bf16)(x1 * c1 - x2 * s1);
    base[d + 64] = (bf16)(x2 * c2 + x1 * s2);
  }
}

// v-part of qkv -> Vt (B,KVH,HD,K) bf16
__global__ void vtrans(const bf16* __restrict__ qkv, bf16* __restrict__ Vt) {
  __shared__ bf16 t[32][33];
  const int bz = blockIdx.z, b = bz >> 2, kv = bz & 3;
  const int k0 = blockIdx.x * 32, d0 = blockIdx.y * 32;
  for (int rr = threadIdx.y; rr < 32; rr += 8)
    t[rr][threadIdx.x] =
        qkv[(int64_t)(b * cK + k0 + rr) * QKVW + cH * cHD + cKVH * cHD + kv * cHD + d0 + threadIdx.x];
  __syncthreads();
  for (int rr = threadIdx.y; rr < 32; rr += 8)
    Vt[((int64_t)(b * cKVH + kv) * cHD + d0 + rr) * cK + k0 + threadIdx.x] = t[threadIdx.x][rr];
}

}  // namespace

extern "C" void kernel_launch(void* const* d_in, const int* in_sizes, int n_in,
                              void* d_out, int out_size, void* d_ws, size_t ws_size,
                              hipStream_t stream) {
  const float* hidden = (const float*)d_in[0];
  const int* topk = (const int*)d_in[1];
  const float* gating = (const float*)d_in[2];
  const float* cosb = (const float*)d_in[3];
  const float* sinb = (const float*)d_in[4];
  const float* Wq = (const float*)d_in[5];
  const float* bq = (const float*)d_in[6];
  const float* Wk = (const float*)d_in[7];
  const float* bk = (const float*)d_in[8];
  const float* Wv = (const float*)d_in[9];
  const float* bv = (const float*)d_in[10];
  const float* Wo = (const float*)d_in[11];
  const float* wg = (const float*)d_in[12];
  const float* wu = (const float*)d_in[13];
  const float* wd = (const float*)d_in[14];
  const float* ln1 = (const float*)d_in[15];
  const float* ln2 = (const float*)d_in[16];
  float* out = (float*)d_out;
  (void)in_sizes; (void)n_in; (void)out_size; (void)ws_size;

  char* ws = (char*)d_ws;
  size_t off = 0;
  auto alloc = [&](size_t bytes) {
    char* p = ws + off;
    off += (bytes + 255) & ~(size_t)255;
    return p;
  };
  bf16* wt_qkv = (bf16*)alloc((size_t)QKVW * cD * 2);
  bf16* wt_o = (bf16*)alloc((size_t)cD * cD * 2);
  bf16* wt_g = (bf16*)alloc((size_t)cFF * cD * 2);
  bf16* wt_u = (bf16*)alloc((size_t)cFF * cD * 2);
  bf16* wt_d = (bf16*)alloc((size_t)cD * cFF * 2);
  float* bias_cat = (float*)alloc((size_t)QKVW * 4);
  bf16* hbuf = (bf16*)alloc((size_t)cM * cD * 2);
  bf16* qkv = (bf16*)alloc((size_t)cM * QKVW * 2);
  bf16* vt = (bf16*)alloc((size_t)cB * cKVH * cHD * cK * 2);
  bf16* attnout = (bf16*)alloc((size_t)cM * cD * 2);
  float* xbuf = (float*)alloc((size_t)cM * cD * 4);
  bf16* actbuf = (bf16*)alloc((size_t)cM * cFF * 2);
  unsigned char* flags = (unsigned char*)alloc((size_t)cB * cT);

  // flags = selected-row mask; copy only unselected rows (EpiDown writes selected)
  hipMemsetAsync(flags, 0, (size_t)cB * cT, stream);
  build_flags<<<cM / 256, 256, 0, stream>>>(topk, flags);
  copy_skip<<<2048, 256, 0, stream>>>((const float4*)hidden, (float4*)out, flags,
                                      (int64_t)cB * cT * cD / 4);

  const dim3 tb(32, 8);
  wconv<<<dim3(cD / 32, cD / 32), tb, 0, stream>>>(Wq, wt_qkv, cD, cD, 0, cD);
  wconv<<<dim3(512 / 32, cD / 32), tb, 0, stream>>>(Wk, wt_qkv, cD, 512, 2048, cD);
  wconv<<<dim3(512 / 32, cD / 32), tb, 0, stream>>>(Wv, wt_qkv, cD, 512, 2560, cD);
  wconv<<<dim3(cD / 32, cD / 32), tb, 0, stream>>>(Wo, wt_o, cD, cD, 0, cD);
  // gate/up weights: fragment-ordered for the direct-to-register gateup kernel
  wconv_frag<<<(cFF / 16) * (cD / 32) * 64 / 256, 256, 0, stream>>>(wg, wt_g, cFF, cD / 32);
  wconv_frag<<<(cFF / 16) * (cD / 32) * 64 / 256, 256, 0, stream>>>(wu, wt_u, cFF, cD / 32);
  wconv<<<dim3(cD / 32, cFF / 32), tb, 0, stream>>>(wd, wt_d, cFF, cD, 0, cFF);
  biascat<<<(QKVW + 255) / 256, 256, 0, stream>>>(bq, bk, bv, bias_cat);

  // gather + rmsnorm1
  rmsnorm_rows<<<cM, 256, 0, stream>>>(hidden, topk, ln1, hbuf);
  // qkv projection (+bias)   [pair-mode pipeline]
  gemm256<256, 2, 4, 5, 2, EpiQKV><<<16 * (QKVW / 256), 512, 0, stream>>>(
      hbuf, cD, wt_qkv, cD, cD, 16, EpiQKV{qkv, bias_cat});
  rope_kernel<<<cM, 256, 0, stream>>>(qkv, cosb, sinb, topk);
  vtrans<<<dim3(cK / 32, cHD / 32, cB * cKVH), tb, 0, stream>>>(qkv, vt);

  // fused flash attention (replaces S-GEMM + softmax + PV)
  flash_attn<<<dim3(cK / 64, cH, cB), 256, 0, stream>>>(qkv, vt, attnout);

  // o-proj + gathered residual -> x (fp32)   [pair-mode pipeline]
  gemm256<128, 4, 2, 5, 2, EpiOProj><<<16 * (cD / 128), 512, 0, stream>>>(
      attnout, cD, wt_o, cD, cD, 16, EpiOProj{xbuf, hidden, topk});
  // rmsnorm2
  rmsnorm_rows<<<cM, 256, 0, stream>>>(xbuf, nullptr, ln2, hbuf);
  // fused gate+up -> act = silu(gate)*up   [frag-ordered B-in-registers, prefetched]
  gemm_gateup<<<16 * (cFF / 128), 512, 0, stream>>>(hbuf, wt_g, wt_u, actbuf);
  // down + residual + gating + scatter into d_out   [pair-mode pipeline]
  gemm256<128, 4, 2, 5, 2, EpiDown><<<16 * (cD / 128), 512, 0, stream>>>(
      actbuf, cFF, wt_d, cFF, cFF, 16, EpiDown{out, xbuf, hidden, topk, gating});
}

// Round 13
// 851.430 us; speedup vs baseline: 1.0838x; 1.0053x over previous
//
#include <hip/hip_runtime.h>
#include <stdint.h>

typedef __bf16 bf16;
typedef __attribute__((ext_vector_type(8))) __bf16 bf16x8;
typedef __attribute__((ext_vector_type(4))) float f32x4;

namespace {

constexpr int cB = 4, cT = 4096, cD = 2048, cK = 1024, cH = 16, cKVH = 4, cHD = 128, cFF = 8192;
constexpr int cM = cB * cK;                 // 4096 gathered rows
constexpr int QKVW = cH * cHD + 2 * cKVH * cHD; // 3072

__device__ __forceinline__ void load_lds16(const void* g, void* l) {
  __builtin_amdgcn_global_load_lds((const __attribute__((address_space(1))) void*)g,
                                   (__attribute__((address_space(3))) void*)l, 16, 0, 0);
}

template <int N>
__device__ __forceinline__ void waitcnt_vm() {
  if constexpr (N == 0) asm volatile("s_waitcnt vmcnt(0)" ::: "memory");
  else if constexpr (N == 3) asm volatile("s_waitcnt vmcnt(3)" ::: "memory");
  else if constexpr (N == 4) asm volatile("s_waitcnt vmcnt(4)" ::: "memory");
  else if constexpr (N == 6) asm volatile("s_waitcnt vmcnt(6)" ::: "memory");
  else if constexpr (N == 8) asm volatile("s_waitcnt vmcnt(8)" ::: "memory");
  else if constexpr (N == 9) asm volatile("s_waitcnt vmcnt(9)" ::: "memory");
  else if constexpr (N == 12) asm volatile("s_waitcnt vmcnt(12)" ::: "memory");
  else static_assert(N == 0, "unsupported vmcnt literal");
}

// ---------------- block reduce (256 threads = 4 waves) ----------------
template <int OP>  // 0 = sum, 1 = max
__device__ __forceinline__ float blk_reduce(float v) {
  __shared__ float sm[5];
  const int tid = threadIdx.x, lane = tid & 63, wid = tid >> 6;
#pragma unroll
  for (int o = 32; o; o >>= 1) {
    float o2 = __shfl_down(v, o, 64);
    v = OP ? fmaxf(v, o2) : v + o2;
  }
  if (lane == 0) sm[wid] = v;
  __syncthreads();
  if (tid == 0) {
    float r = sm[0];
#pragma unroll
    for (int i = 1; i < 4; ++i) r = OP ? fmaxf(r, sm[i]) : r + sm[i];
    sm[4] = r;
  }
  __syncthreads();
  float r = sm[4];
  __syncthreads();
  return r;
}

// ================= deep-pipelined 256-row MFMA GEMM: C = A * B^T =================
// A: M x Kd row-major (lda), B: N x Kd row-major (ldb). BM=256, BK=32.
// 8 waves (512 thr), WM x WN wave grid, RING-slot LDS ring, counted vmcnt, raw
// barriers, XOR-swizzled LDS (pre-swizzled global src + swizzled ds_read_b128).
// UNROLL=1: prologue D=RING-1 tiles, main waits (D-1)*L; tail = vmcnt(0) + D computes.
// UNROLL=2 (RING=5): two K-steps per barrier; bridge = stage(KT-1), vmcnt(0), 4 computes.
template <int BN, int WM, int WN, int RING, int UNROLL, class Epi>
__global__ __launch_bounds__(512, 2)
void gemm256(const bf16* __restrict__ A, int lda,
             const bf16* __restrict__ Bm, int ldb,
             int Kd, int GM, Epi epi) {
  constexpr int BM = 256;
  constexpr int FM = BM / WM / 16;
  constexpr int FN = BN / WN / 16;
  constexpr int ACALLS = 2;          // 256 rows * 64B / (512 thr * 16B)
  constexpr int BCALLS = BN / 128;
  constexpr int L = ACALLS + BCALLS; // vmem instrs per K-tile per thread
  constexpr int D = RING - 1;        // UNROLL=1 prefetch depth
  constexpr int SLOTA = BM * 64;     // bytes per A K-tile (BK=32 -> 64B rows)
  constexpr int SLOTB = BN * 64;
  constexpr int SLOT = SLOTA + SLOTB;
  __shared__ __align__(16) char lds[RING * SLOT];

  const int tid = threadIdx.x;
  const int lane = tid & 63;
  const int wid = tid >> 6;
  const int l15 = lane & 15, lq = lane >> 4;
  const int wr = wid / WN, wc = wid % WN;

  // per-XCD contiguous chunk (nwg % 8 == 0 for all our launches)
  const int nwg = gridDim.x;
  const int xcd = blockIdx.x & 7, loc = blockIdx.x >> 3;
  const int wg = xcd * (nwg >> 3) + loc;
  // grouped mapping: 8 bm fastest, then bn
  const int GN = nwg / GM;
  const int per = 8 * GN;
  const int g = wg / per, r = wg % per;
  const int bm = g * 8 + (r & 7);
  const int bn = r >> 3;

  const bf16* Abase = A + (int64_t)bm * BM * lda;
  const bf16* Bbase = Bm + (int64_t)bn * BN * ldb;

  // staging: LDS linear chunk -> pre-swizzled global source
  const bf16* srcA[ACALLS];
  int dstA[ACALLS];
#pragma unroll
  for (int c2 = 0; c2 < ACALLS; ++c2) {
    const int chunk = c2 * 512 + tid;
    const int row = chunk >> 2, pc = chunk & 3;
    const int lc = pc ^ ((row >> 1) & 3);
    srcA[c2] = Abase + (int64_t)row * lda + lc * 8;
    dstA[c2] = chunk * 16;
  }
  const bf16* srcB[BCALLS];
  int dstB[BCALLS];
#pragma unroll
  for (int c2 = 0; c2 < BCALLS; ++c2) {
    const int chunk = c2 * 512 + tid;
    const int row = chunk >> 2, pc = chunk & 3;
    const int lc = pc ^ ((row >> 1) & 3);
    srcB[c2] = Bbase + (int64_t)row * ldb + lc * 8;
    dstB[c2] = chunk * 16;
  }

  // fragment read offsets (swizzled)
  int offA[FM], offB[FN];
#pragma unroll
  for (int m = 0; m < FM; ++m) {
    const int row = wr * (BM / WM) + m * 16 + l15;
    offA[m] = row * 64 + (lq ^ ((row >> 1) & 3)) * 16;
  }
#pragma unroll
  for (int n = 0; n < FN; ++n) {
    const int row = wc * (BN / WN) + n * 16 + l15;
    offB[n] = SLOTA + row * 64 + (lq ^ ((row >> 1) & 3)) * 16;
  }

  const int KT = Kd >> 5;
  auto stage = [&](int t) {
    char* sb = lds + (size_t)(t % RING) * SLOT;
#pragma unroll
    for (int c2 = 0; c2 < ACALLS; ++c2)
      load_lds16(srcA[c2] + t * 32, sb + dstA[c2]);
#pragma unroll
    for (int c2 = 0; c2 < BCALLS; ++c2)
      load_lds16(srcB[c2] + t * 32, sb + SLOTA + dstB[c2]);
  };
  auto compute = [&](int t, f32x4 (&acc)[FM][FN]) {
    const char* sb = lds + (size_t)(t % RING) * SLOT;
    bf16x8 av[FM], bv[FN];
#pragma unroll
    for (int m = 0; m < FM; ++m) av[m] = *(const bf16x8*)(sb + offA[m]);
#pragma unroll
    for (int n = 0; n < FN; ++n) bv[n] = *(const bf16x8*)(sb + offB[n]);
    __builtin_amdgcn_s_setprio(1);
#pragma unroll
    for (int m = 0; m < FM; ++m)
#pragma unroll
      for (int n = 0; n < FN; ++n)
        acc[m][n] = __builtin_amdgcn_mfma_f32_16x16x32_bf16(av[m], bv[n], acc[m][n], 0, 0, 0);
    __builtin_amdgcn_s_setprio(0);
  };

  f32x4 acc[FM][FN] = {};

  if constexpr (UNROLL == 1) {
#pragma unroll
    for (int i = 0; i < D; ++i) stage(i);
    waitcnt_vm<(D - 1) * L>();
    __builtin_amdgcn_s_barrier();
    __builtin_amdgcn_sched_barrier(0);
    for (int t = 0; t < KT - D; ++t) {
      stage(t + D);
      compute(t, acc);
      waitcnt_vm<(D - 1) * L>();
      __builtin_amdgcn_s_barrier();
      __builtin_amdgcn_sched_barrier(0);
    }
    // tail: all remaining tiles staged; one full drain, then straight computes
    waitcnt_vm<0>();
    __builtin_amdgcn_s_barrier();
    for (int t = KT - D; t < KT; ++t) compute(t, acc);
  } else {
    static_assert(RING == 5 && UNROLL == 2, "pair mode is RING=5");
#pragma unroll
    for (int i = 0; i < 3; ++i) stage(i);
    waitcnt_vm<L>();  // tiles 0,1 landed (tile 2 may be in flight)
    __builtin_amdgcn_s_barrier();
    __builtin_amdgcn_sched_barrier(0);
    int t = 0;
    for (; t <= KT - 6; t += 2) {
      stage(t + 3);
      stage(t + 4);
      compute(t, acc);
      compute(t + 1, acc);
      waitcnt_vm<L>();  // tiles t+2,t+3 landed; t+4 may fly
      __builtin_amdgcn_s_barrier();
      __builtin_amdgcn_sched_barrier(0);
    }
    // t == KT-4; staged through KT-2
    stage(KT - 1);
    waitcnt_vm<0>();
    __builtin_amdgcn_s_barrier();
    compute(KT - 4, acc);
    compute(KT - 3, acc);
    compute(KT - 2, acc);
    compute(KT - 1, acc);
  }

#pragma unroll
  for (int m = 0; m < FM; ++m) {
    const int r0 = bm * BM + wr * (BM / WM) + m * 16 + lq * 4;
#pragma unroll
    for (int n = 0; n < FN; ++n) {
      const int c1 = bn * BN + wc * (BN / WN) + n * 16 + l15;
#pragma unroll
      for (int j = 0; j < 4; ++j) epi(r0 + j, c1, acc[m][n][j]);
    }
  }
}

// ================= fused gate+up GEMM (LDS dual-B, round-7 proven): ==============
// act = silu(A*Bg^T) * (A*Bu^T). BM=256, BN=128 per matrix, 8 waves 4x2, RING=4
// (128 KB), D=3, L=4 (A:2,G:1,U:1), W=(D-1)*L=8. Dual accumulators; epilogue fuses
// silu(g)*u. [Round 13: reverted from B-in-registers variants — measured 274 vs 279
// (pair) vs 293 (frag-reg) vs 357 (strided-reg); LDS staging wins.]
__global__ __launch_bounds__(512, 2)
void gemm_gateup(const bf16* __restrict__ A, const bf16* __restrict__ Bg,
                 const bf16* __restrict__ Bu, bf16* __restrict__ act) {
  constexpr int BM = 256, BN = 128, WM = 4, WN = 2;
  constexpr int FM = 4, FN = 4;
  constexpr int RING = 4, D = 3, L = 4;
  constexpr int SLOTA = BM * 64, SLOTB = BN * 64;
  constexpr int SLOT = SLOTA + 2 * SLOTB;  // 32 KB
  __shared__ __align__(16) char lds[RING * SLOT];

  const int tid = threadIdx.x;
  const int lane = tid & 63;
  const int wid = tid >> 6;
  const int l15 = lane & 15, lq = lane >> 4;
  const int wr = wid / WN, wc = wid % WN;

  const int nwg = gridDim.x;               // 1024
  const int xcd = blockIdx.x & 7, loc = blockIdx.x >> 3;
  const int wg = xcd * (nwg >> 3) + loc;
  const int GM = 16, GN = nwg / GM;        // 64
  const int per = 8 * GN;
  const int g = wg / per, r = wg % per;
  const int bm = g * 8 + (r & 7);
  const int bn = r >> 3;

  const bf16* Abase = A + (int64_t)bm * BM * cD;
  const bf16* Gbase = Bg + (int64_t)bn * BN * cD;
  const bf16* Ubase = Bu + (int64_t)bn * BN * cD;

  const bf16* srcA[2];
  int dstA[2];
#pragma unroll
  for (int c2 = 0; c2 < 2; ++c2) {
    const int chunk = c2 * 512 + tid;
    const int row = chunk >> 2, pc = chunk & 3;
    const int lc = pc ^ ((row >> 1) & 3);
    srcA[c2] = Abase + (int64_t)row * cD + lc * 8;
    dstA[c2] = chunk * 16;
  }
  const int brow = tid >> 2, bpc = tid & 3;
  const int blc = bpc ^ ((brow >> 1) & 3);
  const bf16* srcG = Gbase + (int64_t)brow * cD + blc * 8;
  const bf16* srcU = Ubase + (int64_t)brow * cD + blc * 8;
  const int dstBo = tid * 16;

  int offA[FM], offB[FN];
#pragma unroll
  for (int m = 0; m < FM; ++m) {
    const int row = wr * 64 + m * 16 + l15;
    offA[m] = row * 64 + (lq ^ ((row >> 1) & 3)) * 16;
  }
#pragma unroll
  for (int n = 0; n < FN; ++n) {
    const int row = wc * 64 + n * 16 + l15;
    offB[n] = row * 64 + (lq ^ ((row >> 1) & 3)) * 16;
  }

  const int KT = cD >> 5;  // 64
  auto stage = [&](int t) {
    char* sb = lds + (size_t)(t % RING) * SLOT;
#pragma unroll
    for (int c2 = 0; c2 < 2; ++c2) load_lds16(srcA[c2] + t * 32, sb + dstA[c2]);
    load_lds16(srcG + t * 32, sb + SLOTA + dstBo);
    load_lds16(srcU + t * 32, sb + SLOTA + SLOTB + dstBo);
  };

  f32x4 accg[FM][FN] = {}, accu[FM][FN] = {};

  auto compute = [&](int t) {
    const char* sb = lds + (size_t)(t % RING) * SLOT;
    bf16x8 av[FM], gv[FN], uv[FN];
#pragma unroll
    for (int m = 0; m < FM; ++m) av[m] = *(const bf16x8*)(sb + offA[m]);
#pragma unroll
    for (int n = 0; n < FN; ++n) gv[n] = *(const bf16x8*)(sb + SLOTA + offB[n]);
#pragma unroll
    for (int n = 0; n < FN; ++n) uv[n] = *(const bf16x8*)(sb + SLOTA + SLOTB + offB[n]);
    __builtin_amdgcn_s_setprio(1);
#pragma unroll
    for (int m = 0; m < FM; ++m)
#pragma unroll
      for (int n = 0; n < FN; ++n) {
        accg[m][n] = __builtin_amdgcn_mfma_f32_16x16x32_bf16(av[m], gv[n], accg[m][n], 0, 0, 0);
        accu[m][n] = __builtin_amdgcn_mfma_f32_16x16x32_bf16(av[m], uv[n], accu[m][n], 0, 0, 0);
      }
    __builtin_amdgcn_s_setprio(0);
  };

#pragma unroll
  for (int i = 0; i < D; ++i) stage(i);
  waitcnt_vm<(D - 1) * L>();
  __builtin_amdgcn_s_barrier();
  __builtin_amdgcn_sched_barrier(0);
  for (int t = 0; t < KT - D; ++t) {
    stage(t + D);
    compute(t);
    waitcnt_vm<(D - 1) * L>();
    __builtin_amdgcn_s_barrier();
    __builtin_amdgcn_sched_barrier(0);
  }
  waitcnt_vm<0>();
  __builtin_amdgcn_s_barrier();
  for (int t = KT - D; t < KT; ++t) compute(t);

#pragma unroll
  for (int m = 0; m < FM; ++m) {
    const int r0 = bm * BM + wr * 64 + m * 16 + lq * 4;
#pragma unroll
    for (int n = 0; n < FN; ++n) {
      const int c1 = bn * BN + wc * 64 + n * 16 + l15;
#pragma unroll
      for (int j = 0; j < 4; ++j) {
        float gvv = accg[m][n][j];
        float s = gvv / (1.f + __expf(-gvv));
        act[(int64_t)(r0 + j) * cFF + c1] = (bf16)(s * accu[m][n][j]);
      }
    }
  }
}

// ---------------- epilogues ----------------
struct EpiQKV {
  bf16* out; const float* bias;
  __device__ void operator()(int r, int c, float v) const {
    out[(int64_t)r * QKVW + c] = (bf16)(v + bias[c]);
  }
};
struct EpiOProj {
  float* x; const float* hidden; const int* topk;
  __device__ void operator()(int r, int c, float v) const {
    int b = r >> 10;
    int t = topk[r];
    x[(int64_t)r * cD + c] = v + hidden[((int64_t)b * cT + t) * cD + c];
  }
};
struct EpiDown {  // x2 = x + acc; upd = sel + (x2-sel)*gate; scatter to d_out
  float* out; const float* x; const float* hidden; const int* topk; const float* gating;
  __device__ void operator()(int r, int c, float v) const {
    int b = r >> 10;
    int t = topk[r];
    float x2 = v + x[(int64_t)r * cD + c];
    int64_t ho = ((int64_t)b * cT + t) * cD + c;
    float sel = hidden[ho];
    out[ho] = sel + (x2 - sel) * gating[r];
  }
};

// ================= fused flash attention =================
// 1D grid 1024 blocks, 256 thr = 4 waves. ROUND-13: XCD-chunked block remap —
// each XCD gets a contiguous 128-block chunk = 1 batch x 8 heads x 16 qtiles, so
// per-XCD KV working set = 2 kvh-groups x 512KB = 1MB << 4MB L2 (default round-robin
// replicated ~8MB of KV across all 8 XCD L2s).
// Each wave owns 16 FULL rows x all 128 kv-cols; shfl_xor over l15 = exact row reduce.
// LDS: sK 32K (Q staged here first) | sP 16K | sV 32K = 80 KB -> 2 blocks/CU.
// All LDS tiles XOR-swizzled (16B chunk ^ row&15) via pre-swizzled global src.
__global__ __launch_bounds__(256, 2) void flash_attn(const bf16* __restrict__ qkv,
                                                     const bf16* __restrict__ vt,
                                                     bf16* __restrict__ outb) {
  constexpr int QB = 64, KVB = 128;
  __shared__ __align__(16) char lds[81920];
  char* sK = lds;            // 32 KB (also Q staging)
  char* sP = lds + 32768;    // 16 KB
  char* sV = lds + 49152;    // 32 KB

  // XCD-chunked bijective remap (nwg = 1024, 128 per XCD)
  const int xcdid = blockIdx.x & 7, locid = blockIdx.x >> 3;
  const int wg = xcdid * 128 + locid;
  const int qt = wg & 15, h = (wg >> 4) & 15, b = wg >> 8;
  const int kvh = h >> 2;
  const int qlo = qt * QB;
  const int tid = threadIdx.x, lane = tid & 63, wid = tid >> 6;
  const int l15 = lane & 15, lq = lane >> 4;
  const int wid16 = wid * 16;  // this wave's 16-row block

  const bf16* qbase = qkv + (int64_t)(b * cK + qlo) * QKVW + h * cHD;
  const bf16* kbase = qkv + (int64_t)(b * cK) * QKVW + cH * cHD + kvh * cHD;
  const bf16* vtbase = vt + (int64_t)(b * cKVH + kvh) * cHD * cK;

  // ---- stage Q (64 rows x 256B) into sK region, read frags to regs ----
#pragma unroll
  for (int c2 = 0; c2 < 4; ++c2) {
    int chunk = c2 * 256 + tid;
    int row = chunk >> 4, c16 = chunk & 15;
    load_lds16(qbase + (int64_t)row * QKVW + (c16 ^ (row & 15)) * 8, sK + chunk * 16);
  }
  __syncthreads();
  bf16x8 qf[4];
  {
    const int row = wid16 + l15;
#pragma unroll
    for (int kt = 0; kt < 4; ++kt)
      qf[kt] = *(const bf16x8*)(sK + row * 256 + (((kt * 4 + lq) ^ (row & 15)) * 16));
  }
  __syncthreads();  // all Q reads complete before K staging overwrites sK

  f32x4 oacc[8] = {};
  float m_run[4], l_run[4];
#pragma unroll
  for (int j = 0; j < 4; ++j) { m_run[j] = -3.0e38f; l_run[j] = 0.f; }

  const int jmax = (qlo + QB - 1) >> 7;
  const float sl2e = 0.08838834764831845f * 1.44269504088896f;  // scale * log2(e)

  for (int jj = 0; jj <= jmax; ++jj) {
    // stage K tile (128 rows x 256B) and Vt tile (128 d-rows x 256B)
#pragma unroll
    for (int c2 = 0; c2 < 8; ++c2) {
      int chunk = c2 * 256 + tid;
      int row = chunk >> 4, c16 = chunk & 15;
      int cs = (c16 ^ (row & 15)) * 8;
      load_lds16(kbase + (int64_t)(jj * KVB + row) * QKVW + cs, sK + chunk * 16);
      load_lds16(vtbase + (int64_t)row * cK + jj * KVB + cs, sV + chunk * 16);
    }
    __syncthreads();

    // S = Q K^T : rows = this wave's 16 q-rows, cols = all 128 kv of this tile
    f32x4 sacc[8] = {};
#pragma unroll
    for (int kt = 0; kt < 4; ++kt) {
      bf16x8 bv[8];
#pragma unroll
      for (int n = 0; n < 8; ++n) {
        int rk = n * 16 + l15;
        bv[n] = *(const bf16x8*)(sK + rk * 256 + (((kt * 4 + lq) ^ (rk & 15)) * 16));
      }
#pragma unroll
      for (int n = 0; n < 8; ++n)
        sacc[n] = __builtin_amdgcn_mfma_f32_16x16x32_bf16(qf[kt], bv[n], sacc[n], 0, 0, 0);
    }

    // causal mask on diagonal tile
    if (jj == jmax) {
#pragma unroll
      for (int n = 0; n < 8; ++n)
#pragma unroll
        for (int j = 0; j < 4; ++j) {
          int qrow = qlo + wid16 + lq * 4 + j;
          int kcol = jj * KVB + n * 16 + l15;
          if (kcol > qrow) sacc[n][j] = -3.0e38f;
        }
    }

    // online softmax: lane owns rows (lq*4+j); full row = 8 n-frags x 16 l15 lanes
#pragma unroll
    for (int j = 0; j < 4; ++j) {
      float mx = sacc[0][j];
#pragma unroll
      for (int n = 1; n < 8; ++n) mx = fmaxf(mx, sacc[n][j]);
#pragma unroll
      for (int off = 1; off < 16; off <<= 1) mx = fmaxf(mx, __shfl_xor(mx, off, 64));
      float mnew = fmaxf(m_run[j], mx);
      float corr = exp2f((m_run[j] - mnew) * sl2e);
      m_run[j] = mnew;
      float ps = 0.f;
#pragma unroll
      for (int n = 0; n < 8; ++n) {
        float p = exp2f((sacc[n][j] - mnew) * sl2e);
        sacc[n][j] = p;
        ps += p;
      }
#pragma unroll
      for (int off = 1; off < 16; off <<= 1) ps += __shfl_xor(ps, off, 64);
      l_run[j] = l_run[j] * corr + ps;
#pragma unroll
      for (int n = 0; n < 8; ++n) oacc[n][j] *= corr;
    }

    // P -> LDS (bf16, swizzled); same wave writes and reads its own 16 rows
#pragma unroll
    for (int n = 0; n < 8; ++n)
#pragma unroll
      for (int j = 0; j < 4; ++j) {
        int row = wid16 + lq * 4 + j;
        int col = n * 16 + l15;
        int c16 = (col >> 3) ^ (row & 15);
        *(bf16*)(sP + row * 256 + c16 * 16 + (col & 7) * 2) = (bf16)sacc[n][j];
      }
    __syncthreads();

    // O += P @ Vt^T  (A = P own rows, B = Vt d-rows)
#pragma unroll
    for (int kt = 0; kt < 4; ++kt) {
      const int prow = wid16 + l15;
      bf16x8 av = *(const bf16x8*)(sP + prow * 256 + (((kt * 4 + lq) ^ (prow & 15)) * 16));
      bf16x8 bv[8];
#pragma unroll
      for (int n = 0; n < 8; ++n) {
        int rd = n * 16 + l15;
        bv[n] = *(const bf16x8*)(sV + rd * 256 + (((kt * 4 + lq) ^ (rd & 15)) * 16));
      }
#pragma unroll
      for (int n = 0; n < 8; ++n)
        oacc[n] = __builtin_amdgcn_mfma_f32_16x16x32_bf16(av, bv[n], oacc[n], 0, 0, 0);
    }
    __syncthreads();  // PV reads of sP/sV done before next stage overwrites
  }

  // O / l -> attnout
#pragma unroll
  for (int j = 0; j < 4; ++j) {
    int row = qlo + wid16 + lq * 4 + j;
    float inv = 1.f / l_run[j];
#pragma unroll
    for (int n = 0; n < 8; ++n) {
      int col = h * cHD + n * 16 + l15;
      outb[((int64_t)b * cK + row) * cD + col] = (bf16)(oacc[n][j] * inv);
    }
  }
}

// ---------------- elementwise / staging kernels ----------------
// copy only UNSELECTED rows (selected rows are fully written by EpiDown's scatter)
__global__ void copy_skip(const float4* __restrict__ s, float4* __restrict__ d,
                          const unsigned char* __restrict__ flags, int64_t n) {
  int64_t i = (int64_t)blockIdx.x * blockDim.x + threadIdx.x;
  const int64_t st = (int64_t)gridDim.x * blockDim.x;
  for (; i < n; i += st) {
    int row = (int)(i >> 9);  // 512 float4 per 2048-float row
    if (!flags[row]) d[i] = s[i];
  }
}

__global__ void build_flags(const int* __restrict__ topk, unsigned char* __restrict__ flags) {
  int r = blockIdx.x * 256 + threadIdx.x;
  if (r < cM) flags[(r >> 10) * cT + topk[r]] = 1;
}

// fp32 (R,C) -> bf16 (C,R) with column offset into a concat buffer
__global__ void wconv(const float* __restrict__ src, bf16* __restrict__ dst,
                      int R, int C, int coff, int ldd) {
  __shared__ float t[32][33];
  const int c0 = blockIdx.x * 32, r0 = blockIdx.y * 32;
  for (int rr = threadIdx.y; rr < 32; rr += 8)
    t[rr][threadIdx.x] = src[(int64_t)(r0 + rr) * C + c0 + threadIdx.x];
  __syncthreads();
  for (int rr = threadIdx.y; rr < 32; rr += 8)
    dst[(int64_t)(c0 + rr + coff) * ldd + r0 + threadIdx.x] = (bf16)t[threadIdx.x][rr];
}

__global__ void biascat(const float* __restrict__ bq, const float* __restrict__ bk,
                        const float* __restrict__ bv, float* __restrict__ o) {
  int i = blockIdx.x * 256 + threadIdx.x;
  if (i < QKVW) o[i] = (i < 2048) ? bq[i] : (i < 2560 ? bk[i - 2048] : bv[i - 2560]);
}

// gather (topk!=null) or direct rows (topk==null) + RMSNorm -> bf16
__global__ void rmsnorm_rows(const float* __restrict__ base, const int* __restrict__ topk,
                             const float* __restrict__ w, bf16* __restrict__ out) {
  const int r = blockIdx.x;
  const float* src;
  if (topk) {
    int t = topk[r];
    src = base + ((int64_t)(r >> 10) * cT + t) * cD;
  } else {
    src = base + (int64_t)r * cD;
  }
  const int tid = threadIdx.x;
  const float4* s4 = (const float4*)src;
  float4 a = s4[tid * 2], b = s4[tid * 2 + 1];
  float ss = a.x * a.x + a.y * a.y + a.z * a.z + a.w * a.w +
             b.x * b.x + b.y * b.y + b.z * b.z + b.w * b.w;
  float tot = blk_reduce<0>(ss);
  float sc = rsqrtf(tot * (1.f / cD) + 1e-6f);
  bf16* o = out + (int64_t)r * cD;
  const int d0 = tid * 8;
  o[d0 + 0] = (bf16)(a.x * sc * w[d0 + 0]);
  o[d0 + 1] = (bf16)(a.y * sc * w[d0 + 1]);
  o[d0 + 2] = (bf16)(a.z * sc * w[d0 + 2]);
  o[d0 + 3] = (bf16)(a.w * sc * w[d0 + 3]);
  o[d0 + 4] = (bf16)(b.x * sc * w[d0 + 4]);
  o[d0 + 5] = (bf16)(b.y * sc * w[d0 + 5]);
  o[d0 + 6] = (bf16)(b.z * sc * w[d0 + 6]);
  o[d0 + 7] = (bf16)(b.w * sc * w[d0 + 7]);
}

__global__ void rope_kernel(bf16* __restrict__ qkv, const float* __restrict__ cosb,
                            const float* __restrict__ sinb, const int* __restrict__ topk) {
  const int r = blockIdx.x;  // b*K + k
  const int b = r >> 10;
  const int t = topk[r];
  const float* cr = cosb + ((int64_t)b * cT + t) * cHD;
  const float* sr = sinb + ((int64_t)b * cT + t) * cHD;
  bf16* rowq = qkv + (int64_t)r * QKVW;
  for (int p = threadIdx.x; p < (cH + cKVH) * 64; p += 256) {
    int hh = p >> 6, d = p & 63;
    bf16* base = (hh < cH) ? (rowq + hh * cHD) : (rowq + cH * cHD + (hh - cH) * cHD);
    float x1 = (float)base[d], x2 = (float)base[d + 64];
    float c1 = cr[d], s1 = sr[d], c2 = cr[d + 64], s2 = sr[d + 64];
    base[d] = (bf16)(x1 * c1 - x2 * s1);
    base[d + 64] = (bf16)(x2 * c2 + x1 * s2);
  }
}

// v-part of qkv -> Vt (B,KVH,HD,K) bf16
__global__ void vtrans(const bf16* __restrict__ qkv, bf16* __restrict__ Vt) {
  __shared__ bf16 t[32][33];
  const int bz = blockIdx.z, b = bz >> 2, kv = bz & 3;
  const int k0 = blockIdx.x * 32, d0 = blockIdx.y * 32;
  for (int rr = threadIdx.y; rr < 32; rr += 8)
    t[rr][threadIdx.x] =
        qkv[(int64_t)(b * cK + k0 + rr) * QKVW + cH * cHD + cKVH * cHD + kv * cHD + d0 + threadIdx.x];
  __syncthreads();
  for (int rr = threadIdx.y; rr < 32; rr += 8)
    Vt[((int64_t)(b * cKVH + kv) * cHD + d0 + rr) * cK + k0 + threadIdx.x] = t[threadIdx.x][rr];
}

}  // namespace

extern "C" void kernel_launch(void* const* d_in, const int* in_sizes, int n_in,
                              void* d_out, int out_size, void* d_ws, size_t ws_size,
                              hipStream_t stream) {
  const float* hidden = (const float*)d_in[0];
  const int* topk = (const int*)d_in[1];
  const float* gating = (const float*)d_in[2];
  const float* cosb = (const float*)d_in[3];
  const float* sinb = (const float*)d_in[4];
  const float* Wq = (const float*)d_in[5];
  const float* bq = (const float*)d_in[6];
  const float* Wk = (const float*)d_in[7];
  const float* bk = (const float*)d_in[8];
  const float* Wv = (const float*)d_in[9];
  const float* bv = (const float*)d_in[10];
  const float* Wo = (const float*)d_in[11];
  const float* wg = (const float*)d_in[12];
  const float* wu = (const float*)d_in[13];
  const float* wd = (const float*)d_in[14];
  const float* ln1 = (const float*)d_in[15];
  const float* ln2 = (const float*)d_in[16];
  float* out = (float*)d_out;
  (void)in_sizes; (void)n_in; (void)out_size; (void)ws_size;

  char* ws = (char*)d_ws;
  size_t off = 0;
  auto alloc = [&](size_t bytes) {
    char* p = ws + off;
    off += (bytes + 255) & ~(size_t)255;
    return p;
  };
  bf16* wt_qkv = (bf16*)alloc((size_t)QKVW * cD * 2);
  bf16* wt_o = (bf16*)alloc((size_t)cD * cD * 2);
  bf16* wt_g = (bf16*)alloc((size_t)cFF * cD * 2);
  bf16* wt_u = (bf16*)alloc((size_t)cFF * cD * 2);
  bf16* wt_d = (bf16*)alloc((size_t)cD * cFF * 2);
  float* bias_cat = (float*)alloc((size_t)QKVW * 4);
  bf16* hbuf = (bf16*)alloc((size_t)cM * cD * 2);
  bf16* qkv = (bf16*)alloc((size_t)cM * QKVW * 2);
  bf16* vt = (bf16*)alloc((size_t)cB * cKVH * cHD * cK * 2);
  bf16* attnout = (bf16*)alloc((size_t)cM * cD * 2);
  float* xbuf = (float*)alloc((size_t)cM * cD * 4);
  bf16* actbuf = (bf16*)alloc((size_t)cM * cFF * 2);
  unsigned char* flags = (unsigned char*)alloc((size_t)cB * cT);

  // flags = selected-row mask; copy only unselected rows (EpiDown writes selected)
  hipMemsetAsync(flags, 0, (size_t)cB * cT, stream);
  build_flags<<<cM / 256, 256, 0, stream>>>(topk, flags);
  copy_skip<<<2048, 256, 0, stream>>>((const float4*)hidden, (float4*)out, flags,
                                      (int64_t)cB * cT * cD / 4);

  const dim3 tb(32, 8);
  wconv<<<dim3(cD / 32, cD / 32), tb, 0, stream>>>(Wq, wt_qkv, cD, cD, 0, cD);
  wconv<<<dim3(512 / 32, cD / 32), tb, 0, stream>>>(Wk, wt_qkv, cD, 512, 2048, cD);
  wconv<<<dim3(512 / 32, cD / 32), tb, 0, stream>>>(Wv, wt_qkv, cD, 512, 2560, cD);
  wconv<<<dim3(cD / 32, cD / 32), tb, 0, stream>>>(Wo, wt_o, cD, cD, 0, cD);
  wconv<<<dim3(cFF / 32, cD / 32), tb, 0, stream>>>(wg, wt_g, cD, cFF, 0, cD);
  wconv<<<dim3(cFF / 32, cD / 32), tb, 0, stream>>>(wu, wt_u, cD, cFF, 0, cD);
  wconv<<<dim3(cD / 32, cFF / 32), tb, 0, stream>>>(wd, wt_d, cFF, cD, 0, cFF);
  biascat<<<(QKVW + 255) / 256, 256, 0, stream>>>(bq, bk, bv, bias_cat);

  // gather + rmsnorm1
  rmsnorm_rows<<<cM, 256, 0, stream>>>(hidden, topk, ln1, hbuf);
  // qkv projection (+bias)   [pair-mode pipeline]
  gemm256<256, 2, 4, 5, 2, EpiQKV><<<16 * (QKVW / 256), 512, 0, stream>>>(
      hbuf, cD, wt_qkv, cD, cD, 16, EpiQKV{qkv, bias_cat});
  rope_kernel<<<cM, 256, 0, stream>>>(qkv, cosb, sinb, topk);
  vtrans<<<dim3(cK / 32, cHD / 32, cB * cKVH), tb, 0, stream>>>(qkv, vt);

  // fused flash attention (1D grid, XCD-chunked remap for KV L2 locality)
  flash_attn<<<1024, 256, 0, stream>>>(qkv, vt, attnout);

  // o-proj + gathered residual -> x (fp32)   [pair-mode pipeline]
  gemm256<128, 4, 2, 5, 2, EpiOProj><<<16 * (cD / 128), 512, 0, stream>>>(
      attnout, cD, wt_o, cD, cD, 16, EpiOProj{xbuf, hidden, topk});
  // rmsnorm2
  rmsnorm_rows<<<cM, 256, 0, stream>>>(xbuf, nullptr, ln2, hbuf);
  // fused gate+up -> act = silu(gate)*up   [LDS dual-B, round-7 proven]
  gemm_gateup<<<16 * (cFF / 128), 512, 0, stream>>>(hbuf, wt_g, wt_u, actbuf);
  // down + residual + gating + scatter into d_out   [pair-mode pipeline]
  gemm256<128, 4, 2, 5, 2, EpiDown><<<16 * (cD / 128), 512, 0, stream>>>(
      actbuf, cFF, wt_d, cFF, cFF, 16, EpiDown{out, xbuf, hidden, topk, gating});
}

// Round 15
// 835.900 us; speedup vs baseline: 1.1039x; 1.0186x over previous
//
#include <hip/hip_runtime.h>
#include <stdint.h>

typedef __bf16 bf16;
typedef __attribute__((ext_vector_type(8))) __bf16 bf16x8;
typedef __attribute__((ext_vector_type(4))) float f32x4;

namespace {

constexpr int cB = 4, cT = 4096, cD = 2048, cK = 1024, cH = 16, cKVH = 4, cHD = 128, cFF = 8192;
constexpr int cM = cB * cK;                 // 4096 gathered rows
constexpr int QKVW = cH * cHD + 2 * cKVH * cHD; // 3072

__device__ __forceinline__ void load_lds16(const void* g, void* l) {
  __builtin_amdgcn_global_load_lds((const __attribute__((address_space(1))) void*)g,
                                   (__attribute__((address_space(3))) void*)l, 16, 0, 0);
}

template <int N>
__device__ __forceinline__ void waitcnt_vm() {
  if constexpr (N == 0) asm volatile("s_waitcnt vmcnt(0)" ::: "memory");
  else if constexpr (N == 2) asm volatile("s_waitcnt vmcnt(2)" ::: "memory");
  else if constexpr (N == 3) asm volatile("s_waitcnt vmcnt(3)" ::: "memory");
  else if constexpr (N == 4) asm volatile("s_waitcnt vmcnt(4)" ::: "memory");
  else if constexpr (N == 6) asm volatile("s_waitcnt vmcnt(6)" ::: "memory");
  else if constexpr (N == 8) asm volatile("s_waitcnt vmcnt(8)" ::: "memory");
  else static_assert(N == 0, "unsupported vmcnt literal");
}

// ---------------- block reduce (256 threads = 4 waves) ----------------
template <int OP>  // 0 = sum, 1 = max
__device__ __forceinline__ float blk_reduce(float v) {
  __shared__ float sm[5];
  const int tid = threadIdx.x, lane = tid & 63, wid = tid >> 6;
#pragma unroll
  for (int o = 32; o; o >>= 1) {
    float o2 = __shfl_down(v, o, 64);
    v = OP ? fmaxf(v, o2) : v + o2;
  }
  if (lane == 0) sm[wid] = v;
  __syncthreads();
  if (tid == 0) {
    float r = sm[0];
#pragma unroll
    for (int i = 1; i < 4; ++i) r = OP ? fmaxf(r, sm[i]) : r + sm[i];
    sm[4] = r;
  }
  __syncthreads();
  float r = sm[4];
  __syncthreads();
  return r;
}

// ================= deep-pipelined 256-row MFMA GEMM: C = A * B^T =================
// (pair-mode, proven) — used for QKV / OProj / Down.
template <int BN, int WM, int WN, int RING, int UNROLL, class Epi>
__global__ __launch_bounds__(512, 2)
void gemm256(const bf16* __restrict__ A, int lda,
             const bf16* __restrict__ Bm, int ldb,
             int Kd, int GM, Epi epi) {
  constexpr int BM = 256;
  constexpr int FM = BM / WM / 16;
  constexpr int FN = BN / WN / 16;
  constexpr int ACALLS = 2;
  constexpr int BCALLS = BN / 128;
  constexpr int L = ACALLS + BCALLS;
  constexpr int D = RING - 1;
  constexpr int SLOTA = BM * 64;
  constexpr int SLOTB = BN * 64;
  constexpr int SLOT = SLOTA + SLOTB;
  __shared__ __align__(16) char lds[RING * SLOT];

  const int tid = threadIdx.x;
  const int lane = tid & 63;
  const int wid = tid >> 6;
  const int l15 = lane & 15, lq = lane >> 4;
  const int wr = wid / WN, wc = wid % WN;

  const int nwg = gridDim.x;
  const int xcd = blockIdx.x & 7, loc = blockIdx.x >> 3;
  const int wg = xcd * (nwg >> 3) + loc;
  const int GN = nwg / GM;
  const int per = 8 * GN;
  const int g = wg / per, r = wg % per;
  const int bm = g * 8 + (r & 7);
  const int bn = r >> 3;

  const bf16* Abase = A + (int64_t)bm * BM * lda;
  const bf16* Bbase = Bm + (int64_t)bn * BN * ldb;

  const bf16* srcA[ACALLS];
  int dstA[ACALLS];
#pragma unroll
  for (int c2 = 0; c2 < ACALLS; ++c2) {
    const int chunk = c2 * 512 + tid;
    const int row = chunk >> 2, pc = chunk & 3;
    const int lc = pc ^ ((row >> 1) & 3);
    srcA[c2] = Abase + (int64_t)row * lda + lc * 8;
    dstA[c2] = chunk * 16;
  }
  const bf16* srcB[BCALLS];
  int dstB[BCALLS];
#pragma unroll
  for (int c2 = 0; c2 < BCALLS; ++c2) {
    const int chunk = c2 * 512 + tid;
    const int row = chunk >> 2, pc = chunk & 3;
    const int lc = pc ^ ((row >> 1) & 3);
    srcB[c2] = Bbase + (int64_t)row * ldb + lc * 8;
    dstB[c2] = chunk * 16;
  }

  int offA[FM], offB[FN];
#pragma unroll
  for (int m = 0; m < FM; ++m) {
    const int row = wr * (BM / WM) + m * 16 + l15;
    offA[m] = row * 64 + (lq ^ ((row >> 1) & 3)) * 16;
  }
#pragma unroll
  for (int n = 0; n < FN; ++n) {
    const int row = wc * (BN / WN) + n * 16 + l15;
    offB[n] = SLOTA + row * 64 + (lq ^ ((row >> 1) & 3)) * 16;
  }

  const int KT = Kd >> 5;
  auto stage = [&](int t) {
    char* sb = lds + (size_t)(t % RING) * SLOT;
#pragma unroll
    for (int c2 = 0; c2 < ACALLS; ++c2)
      load_lds16(srcA[c2] + t * 32, sb + dstA[c2]);
#pragma unroll
    for (int c2 = 0; c2 < BCALLS; ++c2)
      load_lds16(srcB[c2] + t * 32, sb + SLOTA + dstB[c2]);
  };
  auto compute = [&](int t, f32x4 (&acc)[FM][FN]) {
    const char* sb = lds + (size_t)(t % RING) * SLOT;
    bf16x8 av[FM], bv[FN];
#pragma unroll
    for (int m = 0; m < FM; ++m) av[m] = *(const bf16x8*)(sb + offA[m]);
#pragma unroll
    for (int n = 0; n < FN; ++n) bv[n] = *(const bf16x8*)(sb + offB[n]);
    __builtin_amdgcn_s_setprio(1);
#pragma unroll
    for (int m = 0; m < FM; ++m)
#pragma unroll
      for (int n = 0; n < FN; ++n)
        acc[m][n] = __builtin_amdgcn_mfma_f32_16x16x32_bf16(av[m], bv[n], acc[m][n], 0, 0, 0);
    __builtin_amdgcn_s_setprio(0);
  };

  f32x4 acc[FM][FN] = {};

  if constexpr (UNROLL == 1) {
#pragma unroll
    for (int i = 0; i < D; ++i) stage(i);
    waitcnt_vm<(D - 1) * L>();
    __builtin_amdgcn_s_barrier();
    __builtin_amdgcn_sched_barrier(0);
    for (int t = 0; t < KT - D; ++t) {
      stage(t + D);
      compute(t, acc);
      waitcnt_vm<(D - 1) * L>();
      __builtin_amdgcn_s_barrier();
      __builtin_amdgcn_sched_barrier(0);
    }
    waitcnt_vm<0>();
    __builtin_amdgcn_s_barrier();
    for (int t = KT - D; t < KT; ++t) compute(t, acc);
  } else {
    static_assert(RING == 5 && UNROLL == 2, "pair mode is RING=5");
#pragma unroll
    for (int i = 0; i < 3; ++i) stage(i);
    waitcnt_vm<L>();
    __builtin_amdgcn_s_barrier();
    __builtin_amdgcn_sched_barrier(0);
    int t = 0;
    for (; t <= KT - 6; t += 2) {
      stage(t + 3);
      stage(t + 4);
      compute(t, acc);
      compute(t + 1, acc);
      waitcnt_vm<L>();
      __builtin_amdgcn_s_barrier();
      __builtin_amdgcn_sched_barrier(0);
    }
    stage(KT - 1);
    waitcnt_vm<0>();
    __builtin_amdgcn_s_barrier();
    compute(KT - 4, acc);
    compute(KT - 3, acc);
    compute(KT - 2, acc);
    compute(KT - 1, acc);
  }

#pragma unroll
  for (int m = 0; m < FM; ++m) {
    const int r0 = bm * BM + wr * (BM / WM) + m * 16 + lq * 4;
#pragma unroll
    for (int n = 0; n < FN; ++n) {
      const int c1 = bn * BN + wc * (BN / WN) + n * 16 + l15;
#pragma unroll
      for (int j = 0; j < 4; ++j) epi(r0 + j, c1, acc[m][n][j]);
    }
  }
}

// ========== 8-phase fused gate+up GEMM (m201 schedule port) ==========
// B' = gate/up weights interleaved 16-rows-G / 16-rows-U (wconv_gu), making this an
// exact 256x256 single-B GEMM: wave (wr,wc) owns rows wr*128..+128, B'-rows wc*64..+64;
// its 4 col-frags alternate G,U,G,U over the SAME output cols -> silu pairing is
// same-wave same-lane: silu(acc[m][2p]) * acc[m][2p+1].
// Schedule: BK=64, double-buffered LDS (2 bufs x 8 quarters x 8 KB = 128 KB), 4 phases
// per K-tile: {ds-read subtile + stage 1 quarter-pair -> barrier -> 16 MFMA (setprio)
// -> barrier}. Quadrant order (qr,qc): (0,0),(0,1),(1,1),(1,0). Stages during tile t
// fill buf^1 with tile t+1 quarters in need-order: p0:Bq01, p1:Bq23, p2:Aq0+Aq2,
// p3:Aq1+Aq3 (1 load/thread per quarter).
// vmcnt ledger (per-thread, 2 loads per stage-pair): tile-t needs {all Bq, Aq0,Aq2} by
// t-p0 and {Aq1,Aq3} by t-p2. Guards placed ONE PHASE AHEAD of need:
//   end-p1: vmcnt(4)  [outstanding Aq13(t):2 + Bq01(t+1):2 + Bq23(t+1):2 = 6 -> retires
//                      Aq13(t) before p2's reads]
//   end-p3: vmcnt(2)  [outstanding 8 -> retires Bq01,Bq23,Aq02(t+1) before t+1-p0]
// Never 0 in-loop. Tail tile (no stages): end-p1 -> vmcnt(0). Prologue stages tile 0
// (4 pairs in the same order) + vmcnt(2) + barrier -> loop enters in steady state.
// Swizzle: 16B chunk index ^= (row&7) both sides; verified 2-way (free) on reads.
__global__ __launch_bounds__(512, 2)
void gemm_gateup8(const bf16* __restrict__ A, const bf16* __restrict__ Bgu,
                  bf16* __restrict__ act) {
  constexpr int QSZ = 64 * 128;  // quarter: 64 rows x 128 B = 8 KB
  __shared__ __align__(16) char lds[2 * 8 * QSZ];  // 128 KB

  const int tid = threadIdx.x, lane = tid & 63;
  const int wid = tid >> 6;
  const int l15 = lane & 15, lq = lane >> 4;
  const int wr = wid >> 2, wc = wid & 3;  // 2 x 4 wave grid

  // grouped-XCD mapping (nwg = 1024, GM = 16, bm 8-fastest)
  const int nwg = gridDim.x;
  const int xcd = blockIdx.x & 7, loc = blockIdx.x >> 3;
  const int wg = xcd * (nwg >> 3) + loc;
  const int GM = 16, GN = nwg / GM;
  const int per = 8 * GN;
  const int g = wg / per, r = wg % per;
  const int bm = g * 8 + (r & 7);
  const int bn = r >> 3;

  const bf16* Abase = A + (int64_t)bm * 256 * cD;
  const bf16* Bbase = Bgu + (int64_t)bn * 256 * cD;

  // staging: thread = one 16B chunk per quarter (quarter = 512 chunks, linear dest)
  const int srow = tid >> 3, spc = tid & 7;
  const int slc = spc ^ (srow & 7);  // pre-swizzled global k-chunk
  const int sdst = tid * 16;
  const bf16* qsrc[8];
#pragma unroll
  for (int q = 0; q < 4; ++q) qsrc[q] = Abase + (int64_t)(q * 64 + srow) * cD + slc * 8;
#pragma unroll
  for (int q = 0; q < 4; ++q) qsrc[4 + q] = Bbase + (int64_t)(q * 64 + srow) * cD + slc * 8;

  auto stageQ = [&](int buf, int q, int kt) {
    load_lds16(qsrc[q] + kt * 64, lds + (size_t)(buf * 8 + q) * QSZ + sdst);
  };

  f32x4 acc[8][4] = {};
  bf16x8 af[4][2], bfr[2][2];

  auto ldA = [&](int buf, int qr) {
    const char* qb = lds + (size_t)(buf * 8 + wr * 2 + qr) * QSZ;
#pragma unroll
    for (int mq = 0; mq < 4; ++mq) {
      const int rr = mq * 16 + l15;
#pragma unroll
      for (int ks = 0; ks < 2; ++ks)
        af[mq][ks] = *(const bf16x8*)(qb + rr * 128 + (((ks * 4 + lq) ^ (rr & 7)) * 16));
    }
  };
  auto ldB = [&](int buf, int qc) {
    const char* qb = lds + (size_t)(buf * 8 + 4 + wc) * QSZ;
#pragma unroll
    for (int nq = 0; nq < 2; ++nq) {
      const int rr = qc * 32 + nq * 16 + l15;
#pragma unroll
      for (int ks = 0; ks < 2; ++ks)
        bfr[nq][ks] = *(const bf16x8*)(qb + rr * 128 + (((ks * 4 + lq) ^ (rr & 7)) * 16));
    }
  };
  auto mfma16 = [&](int qr, int qc) {
    __builtin_amdgcn_s_setprio(1);
#pragma unroll
    for (int ks = 0; ks < 2; ++ks)
#pragma unroll
      for (int mq = 0; mq < 4; ++mq)
#pragma unroll
        for (int nq = 0; nq < 2; ++nq)
          acc[qr * 4 + mq][qc * 2 + nq] = __builtin_amdgcn_mfma_f32_16x16x32_bf16(
              af[mq][ks], bfr[nq][ks], acc[qr * 4 + mq][qc * 2 + nq], 0, 0, 0);
    __builtin_amdgcn_s_setprio(0);
  };

  const int KT = cD >> 6;  // 32 K-tiles of 64

  // prologue: tile 0 quarters in retirement order
  stageQ(0, 4, 0); stageQ(0, 5, 0);   // Bq0,Bq1
  stageQ(0, 6, 0); stageQ(0, 7, 0);   // Bq2,Bq3
  stageQ(0, 0, 0); stageQ(0, 2, 0);   // Aq0,Aq2
  stageQ(0, 1, 0); stageQ(0, 3, 0);   // Aq1,Aq3
  waitcnt_vm<2>();
  __builtin_amdgcn_s_barrier();

  for (int t = 0; t < KT; ++t) {
    const int buf = t & 1, nb = buf ^ 1;
    const bool more = (t + 1 < KT);
    // phase 0: quadrant (0,0)
    ldA(buf, 0);
    ldB(buf, 0);
    if (more) { stageQ(nb, 4, t + 1); stageQ(nb, 5, t + 1); }
    __builtin_amdgcn_s_barrier();
    mfma16(0, 0);
    __builtin_amdgcn_s_barrier();
    // phase 1: quadrant (0,1)
    ldB(buf, 1);
    if (more) { stageQ(nb, 6, t + 1); stageQ(nb, 7, t + 1); }
    __builtin_amdgcn_s_barrier();
    mfma16(0, 1);
    if (more) waitcnt_vm<4>();
    else      waitcnt_vm<0>();  // tail: retire Aq1,Aq3 of the last tile
    __builtin_amdgcn_s_barrier();
    // phase 2: quadrant (1,1)
    ldA(buf, 1);
    if (more) { stageQ(nb, 0, t + 1); stageQ(nb, 2, t + 1); }
    __builtin_amdgcn_s_barrier();
    mfma16(1, 1);
    __builtin_amdgcn_s_barrier();
    // phase 3: quadrant (1,0)
    ldB(buf, 0);
    if (more) { stageQ(nb, 1, t + 1); stageQ(nb, 3, t + 1); }
    __builtin_amdgcn_s_barrier();
    mfma16(1, 0);
    if (more) waitcnt_vm<2>();
    __builtin_amdgcn_s_barrier();
  }

  // epilogue: pair G (n=2p) with U (n=2p+1), silu-fuse, store
#pragma unroll
  for (int m = 0; m < 8; ++m) {
    const int row = bm * 256 + wr * 128 + (m >> 2) * 64 + (m & 3) * 16 + lq * 4;
#pragma unroll
    for (int p = 0; p < 2; ++p) {
      const int col = bn * 128 + wc * 32 + p * 16 + l15;
#pragma unroll
      for (int j = 0; j < 4; ++j) {
        float gv = acc[m][2 * p][j];
        float s = gv / (1.f + __expf(-gv));
        act[(int64_t)(row + j) * cFF + col] = (bf16)(s * acc[m][2 * p + 1][j]);
      }
    }
  }
}

// ---------------- epilogues ----------------
struct EpiQKV {
  bf16* out; const float* bias;
  __device__ void operator()(int r, int c, float v) const {
    out[(int64_t)r * QKVW + c] = (bf16)(v + bias[c]);
  }
};
struct EpiOProj {
  float* x; const float* hidden; const int* topk;
  __device__ void operator()(int r, int c, float v) const {
    int b = r >> 10;
    int t = topk[r];
    x[(int64_t)r * cD + c] = v + hidden[((int64_t)b * cT + t) * cD + c];
  }
};
struct EpiDown {  // x2 = x + acc; upd = sel + (x2-sel)*gate; scatter to d_out
  float* out; const float* x; const float* hidden; const int* topk; const float* gating;
  __device__ void operator()(int r, int c, float v) const {
    int b = r >> 10;
    int t = topk[r];
    float x2 = v + x[(int64_t)r * cD + c];
    int64_t ho = ((int64_t)b * cT + t) * cD + c;
    float sel = hidden[ho];
    out[ho] = sel + (x2 - sel) * gating[r];
  }
};

// ================= fused flash attention (XCD-chunked remap) =================
__global__ __launch_bounds__(256, 2) void flash_attn(const bf16* __restrict__ qkv,
                                                     const bf16* __restrict__ vt,
                                                     bf16* __restrict__ outb) {
  constexpr int QB = 64, KVB = 128;
  __shared__ __align__(16) char lds[81920];
  char* sK = lds;            // 32 KB (also Q staging)
  char* sP = lds + 32768;    // 16 KB
  char* sV = lds + 49152;    // 32 KB

  const int xcdid = blockIdx.x & 7, locid = blockIdx.x >> 3;
  const int wg = xcdid * 128 + locid;
  const int qt = wg & 15, h = (wg >> 4) & 15, b = wg >> 8;
  const int kvh = h >> 2;
  const int qlo = qt * QB;
  const int tid = threadIdx.x, lane = tid & 63, wid = tid >> 6;
  const int l15 = lane & 15, lq = lane >> 4;
  const int wid16 = wid * 16;

  const bf16* qbase = qkv + (int64_t)(b * cK + qlo) * QKVW + h * cHD;
  const bf16* kbase = qkv + (int64_t)(b * cK) * QKVW + cH * cHD + kvh * cHD;
  const bf16* vtbase = vt + (int64_t)(b * cKVH + kvh) * cHD * cK;

#pragma unroll
  for (int c2 = 0; c2 < 4; ++c2) {
    int chunk = c2 * 256 + tid;
    int row = chunk >> 4, c16 = chunk & 15;
    load_lds16(qbase + (int64_t)row * QKVW + (c16 ^ (row & 15)) * 8, sK + chunk * 16);
  }
  __syncthreads();
  bf16x8 qf[4];
  {
    const int row = wid16 + l15;
#pragma unroll
    for (int kt = 0; kt < 4; ++kt)
      qf[kt] = *(const bf16x8*)(sK + row * 256 + (((kt * 4 + lq) ^ (row & 15)) * 16));
  }
  __syncthreads();

  f32x4 oacc[8] = {};
  float m_run[4], l_run[4];
#pragma unroll
  for (int j = 0; j < 4; ++j) { m_run[j] = -3.0e38f; l_run[j] = 0.f; }

  const int jmax = (qlo + QB - 1) >> 7;
  const float sl2e = 0.08838834764831845f * 1.44269504088896f;

  for (int jj = 0; jj <= jmax; ++jj) {
#pragma unroll
    for (int c2 = 0; c2 < 8; ++c2) {
      int chunk = c2 * 256 + tid;
      int row = chunk >> 4, c16 = chunk & 15;
      int cs = (c16 ^ (row & 15)) * 8;
      load_lds16(kbase + (int64_t)(jj * KVB + row) * QKVW + cs, sK + chunk * 16);
      load_lds16(vtbase + (int64_t)row * cK + jj * KVB + cs, sV + chunk * 16);
    }
    __syncthreads();

    f32x4 sacc[8] = {};
#pragma unroll
    for (int kt = 0; kt < 4; ++kt) {
      bf16x8 bv[8];
#pragma unroll
      for (int n = 0; n < 8; ++n) {
        int rk = n * 16 + l15;
        bv[n] = *(const bf16x8*)(sK + rk * 256 + (((kt * 4 + lq) ^ (rk & 15)) * 16));
      }
#pragma unroll
      for (int n = 0; n < 8; ++n)
        sacc[n] = __builtin_amdgcn_mfma_f32_16x16x32_bf16(qf[kt], bv[n], sacc[n], 0, 0, 0);
    }

    if (jj == jmax) {
#pragma unroll
      for (int n = 0; n < 8; ++n)
#pragma unroll
        for (int j = 0; j < 4; ++j) {
          int qrow = qlo + wid16 + lq * 4 + j;
          int kcol = jj * KVB + n * 16 + l15;
          if (kcol > qrow) sacc[n][j] = -3.0e38f;
        }
    }

#pragma unroll
    for (int j = 0; j < 4; ++j) {
      float mx = sacc[0][j];
#pragma unroll
      for (int n = 1; n < 8; ++n) mx = fmaxf(mx, sacc[n][j]);
#pragma unroll
      for (int off = 1; off < 16; off <<= 1) mx = fmaxf(mx, __shfl_xor(mx, off, 64));
      float mnew = fmaxf(m_run[j], mx);
      float corr = exp2f((m_run[j] - mnew) * sl2e);
      m_run[j] = mnew;
      float ps = 0.f;
#pragma unroll
      for (int n = 0; n < 8; ++n) {
        float p = exp2f((sacc[n][j] - mnew) * sl2e);
        sacc[n][j] = p;
        ps += p;
      }
#pragma unroll
      for (int off = 1; off < 16; off <<= 1) ps += __shfl_xor(ps, off, 64);
      l_run[j] = l_run[j] * corr + ps;
#pragma unroll
      for (int n = 0; n < 8; ++n) oacc[n][j] *= corr;
    }

#pragma unroll
    for (int n = 0; n < 8; ++n)
#pragma unroll
      for (int j = 0; j < 4; ++j) {
        int row = wid16 + lq * 4 + j;
        int col = n * 16 + l15;
        int c16 = (col >> 3) ^ (row & 15);
        *(bf16*)(sP + row * 256 + c16 * 16 + (col & 7) * 2) = (bf16)sacc[n][j];
      }
    __syncthreads();

#pragma unroll
    for (int kt = 0; kt < 4; ++kt) {
      const int prow = wid16 + l15;
      bf16x8 av = *(const bf16x8*)(sP + prow * 256 + (((kt * 4 + lq) ^ (prow & 15)) * 16));
      bf16x8 bv[8];
#pragma unroll
      for (int n = 0; n < 8; ++n) {
        int rd = n * 16 + l15;
        bv[n] = *(const bf16x8*)(sV + rd * 256 + (((kt * 4 + lq) ^ (rd & 15)) * 16));
      }
#pragma unroll
      for (int n = 0; n < 8; ++n)
        oacc[n] = __builtin_amdgcn_mfma_f32_16x16x32_bf16(av, bv[n], oacc[n], 0, 0, 0);
    }
    __syncthreads();
  }

#pragma unroll
  for (int j = 0; j < 4; ++j) {
    int row = qlo + wid16 + lq * 4 + j;
    float inv = 1.f / l_run[j];
#pragma unroll
    for (int n = 0; n < 8; ++n) {
      int col = h * cHD + n * 16 + l15;
      outb[((int64_t)b * cK + row) * cD + col] = (bf16)(oacc[n][j] * inv);
    }
  }
}

// ---------------- elementwise / staging kernels ----------------
__global__ void copy_skip(const float4* __restrict__ s, float4* __restrict__ d,
                          const unsigned char* __restrict__ flags, int64_t n) {
  int64_t i = (int64_t)blockIdx.x * blockDim.x + threadIdx.x;
  const int64_t st = (int64_t)gridDim.x * blockDim.x;
  for (; i < n; i += st) {
    int row = (int)(i >> 9);
    if (!flags[row]) d[i] = s[i];
  }
}

__global__ void build_flags(const int* __restrict__ topk, unsigned char* __restrict__ flags) {
  int r = blockIdx.x * 256 + threadIdx.x;
  if (r < cM) flags[(r >> 10) * cT + topk[r]] = 1;
}

// fp32 (R,C) -> bf16 (C,R) with column offset into a concat buffer
__global__ void wconv(const float* __restrict__ src, bf16* __restrict__ dst,
                      int R, int C, int coff, int ldd) {
  __shared__ float t[32][33];
  const int c0 = blockIdx.x * 32, r0 = blockIdx.y * 32;
  for (int rr = threadIdx.y; rr < 32; rr += 8)
    t[rr][threadIdx.x] = src[(int64_t)(r0 + rr) * C + c0 + threadIdx.x];
  __syncthreads();
  for (int rr = threadIdx.y; rr < 32; rr += 8)
    dst[(int64_t)(c0 + rr + coff) * ldd + r0 + threadIdx.x] = (bf16)t[threadIdx.x][rr];
}

// gate/up fp32 (cD, cFF) -> B' bf16 (2*cFF, cD), 16-rows-G / 16-rows-U interleaved:
// gate col c -> B'-row ((c&~15)<<1)|(c&15); up col c -> +16.
__global__ void wconv_gu(const float* __restrict__ srcG, const float* __restrict__ srcU,
                         bf16* __restrict__ dst) {
  __shared__ float t[32][33];
  const float* src = blockIdx.z ? srcU : srcG;
  const int c0 = blockIdx.x * 32, r0 = blockIdx.y * 32;
  for (int rr = threadIdx.y; rr < 32; rr += 8)
    t[rr][threadIdx.x] = src[(int64_t)(r0 + rr) * cFF + c0 + threadIdx.x];
  __syncthreads();
  for (int rr = threadIdx.y; rr < 32; rr += 8) {
    int c = c0 + rr;
    int dr = ((c & ~15) << 1) | (blockIdx.z ? 16 : 0) | (c & 15);
    dst[(int64_t)dr * cD + r0 + threadIdx.x] = (bf16)t[threadIdx.x][rr];
  }
}

__global__ void biascat(const float* __restrict__ bq, const float* __restrict__ bk,
                        const float* __restrict__ bv, float* __restrict__ o) {
  int i = blockIdx.x * 256 + threadIdx.x;
  if (i < QKVW) o[i] = (i < 2048) ? bq[i] : (i < 2560 ? bk[i - 2048] : bv[i - 2560]);
}

__global__ void rmsnorm_rows(const float* __restrict__ base, const int* __restrict__ topk,
                             const float* __restrict__ w, bf16* __restrict__ out) {
  const int r = blockIdx.x;
  const float* src;
  if (topk) {
    int t = topk[r];
    src = base + ((int64_t)(r >> 10) * cT + t) * cD;
  } else {
    src = base + (int64_t)r * cD;
  }
  const int tid = threadIdx.x;
  const float4* s4 = (const float4*)src;
  float4 a = s4[tid * 2], b = s4[tid * 2 + 1];
  float ss = a.x * a.x + a.y * a.y + a.z * a.z + a.w * a.w +
             b.x * b.x + b.y * b.y + b.z * b.z + b.w * b.w;
  float tot = blk_reduce<0>(ss);
  float sc = rsqrtf(tot * (1.f / cD) + 1e-6f);
  bf16* o = out + (int64_t)r * cD;
  const int d0 = tid * 8;
  o[d0 + 0] = (bf16)(a.x * sc * w[d0 + 0]);
  o[d0 + 1] = (bf16)(a.y * sc * w[d0 + 1]);
  o[d0 + 2] = (bf16)(a.z * sc * w[d0 + 2]);
  o[d0 + 3] = (bf16)(a.w * sc * w[d0 + 3]);
  o[d0 + 4] = (bf16)(b.x * sc * w[d0 + 4]);
  o[d0 + 5] = (bf16)(b.y * sc * w[d0 + 5]);
  o[d0 + 6] = (bf16)(b.z * sc * w[d0 + 6]);
  o[d0 + 7] = (bf16)(b.w * sc * w[d0 + 7]);
}

__global__ void rope_kernel(bf16* __restrict__ qkv, const float* __restrict__ cosb,
                            const float* __restrict__ sinb, const int* __restrict__ topk) {
  const int r = blockIdx.x;
  const int b = r >> 10;
  const int t = topk[r];
  const float* cr = cosb + ((int64_t)b * cT + t) * cHD;
  const float* sr = sinb + ((int64_t)b * cT + t) * cHD;
  bf16* rowq = qkv + (int64_t)r * QKVW;
  for (int p = threadIdx.x; p < (cH + cKVH) * 64; p += 256) {
    int hh = p >> 6, d = p & 63;
    bf16* base = (hh < cH) ? (rowq + hh * cHD) : (rowq + cH * cHD + (hh - cH) * cHD);
    float x1 = (float)base[d], x2 = (float)base[d + 64];
    float c1 = cr[d], s1 = sr[d], c2 = cr[d + 64], s2 = sr[d + 64];
    base[d] = (bf16)(x1 * c1 - x2 * s1);
    base[d + 64] = (bf16)(x2 * c2 + x1 * s2);
  }
}

__global__ void vtrans(const bf16* __restrict__ qkv, bf16* __restrict__ Vt) {
  __shared__ bf16 t[32][33];
  const int bz = blockIdx.z, b = bz >> 2, kv = bz & 3;
  const int k0 = blockIdx.x * 32, d0 = blockIdx.y * 32;
  for (int rr = threadIdx.y; rr < 32; rr += 8)
    t[rr][threadIdx.x] =
        qkv[(int64_t)(b * cK + k0 + rr) * QKVW + cH * cHD + cKVH * cHD + kv * cHD + d0 + threadIdx.x];
  __syncthreads();
  for (int rr = threadIdx.y; rr < 32; rr += 8)
    Vt[((int64_t)(b * cKVH + kv) * cHD + d0 + rr) * cK + k0 + threadIdx.x] = t[threadIdx.x][rr];
}

}  // namespace

extern "C" void kernel_launch(void* const* d_in, const int* in_sizes, int n_in,
                              void* d_out, int out_size, void* d_ws, size_t ws_size,
                              hipStream_t stream) {
  const float* hidden = (const float*)d_in[0];
  const int* topk = (const int*)d_in[1];
  const float* gating = (const float*)d_in[2];
  const float* cosb = (const float*)d_in[3];
  const float* sinb = (const float*)d_in[4];
  const float* Wq = (const float*)d_in[5];
  const float* bq = (const float*)d_in[6];
  const float* Wk = (const float*)d_in[7];
  const float* bk = (const float*)d_in[8];
  const float* Wv = (const float*)d_in[9];
  const float* bv = (const float*)d_in[10];
  const float* Wo = (const float*)d_in[11];
  const float* wg = (const float*)d_in[12];
  const float* wu = (const float*)d_in[13];
  const float* wd = (const float*)d_in[14];
  const float* ln1 = (const float*)d_in[15];
  const float* ln2 = (const float*)d_in[16];
  float* out = (float*)d_out;
  (void)in_sizes; (void)n_in; (void)out_size; (void)ws_size;

  char* ws = (char*)d_ws;
  size_t off = 0;
  auto alloc = [&](size_t bytes) {
    char* p = ws + off;
    off += (bytes + 255) & ~(size_t)255;
    return p;
  };
  bf16* wt_qkv = (bf16*)alloc((size_t)QKVW * cD * 2);
  bf16* wt_o = (bf16*)alloc((size_t)cD * cD * 2);
  bf16* wt_gu = (bf16*)alloc((size_t)2 * cFF * cD * 2);
  bf16* wt_d = (bf16*)alloc((size_t)cD * cFF * 2);
  float* bias_cat = (float*)alloc((size_t)QKVW * 4);
  bf16* hbuf = (bf16*)alloc((size_t)cM * cD * 2);
  bf16* qkv = (bf16*)alloc((size_t)cM * QKVW * 2);
  bf16* vt = (bf16*)alloc((size_t)cB * cKVH * cHD * cK * 2);
  bf16* attnout = (bf16*)alloc((size_t)cM * cD * 2);
  float* xbuf = (float*)alloc((size_t)cM * cD * 4);
  bf16* actbuf = (bf16*)alloc((size_t)cM * cFF * 2);
  unsigned char* flags = (unsigned char*)alloc((size_t)cB * cT);

  // flags = selected-row mask; copy only unselected rows (EpiDown writes selected)
  (void)hipMemsetAsync(flags, 0, (size_t)cB * cT, stream);
  build_flags<<<cM / 256, 256, 0, stream>>>(topk, flags);
  copy_skip<<<2048, 256, 0, stream>>>((const float4*)hidden, (float4*)out, flags,
                                      (int64_t)cB * cT * cD / 4);

  const dim3 tb(32, 8);
  wconv<<<dim3(cD / 32, cD / 32), tb, 0, stream>>>(Wq, wt_qkv, cD, cD, 0, cD);
  wconv<<<dim3(512 / 32, cD / 32), tb, 0, stream>>>(Wk, wt_qkv, cD, 512, 2048, cD);
  wconv<<<dim3(512 / 32, cD / 32), tb, 0, stream>>>(Wv, wt_qkv, cD, 512, 2560, cD);
  wconv<<<dim3(cD / 32, cD / 32), tb, 0, stream>>>(Wo, wt_o, cD, cD, 0, cD);
  wconv_gu<<<dim3(cFF / 32, cD / 32, 2), tb, 0, stream>>>(wg, wu, wt_gu);
  wconv<<<dim3(cD / 32, cFF / 32), tb, 0, stream>>>(wd, wt_d, cFF, cD, 0, cFF);
  biascat<<<(QKVW + 255) / 256, 256, 0, stream>>>(bq, bk, bv, bias_cat);

  // gather + rmsnorm1
  rmsnorm_rows<<<cM, 256, 0, stream>>>(hidden, topk, ln1, hbuf);
  // qkv projection (+bias)   [pair-mode pipeline]
  gemm256<256, 2, 4, 5, 2, EpiQKV><<<16 * (QKVW / 256), 512, 0, stream>>>(
      hbuf, cD, wt_qkv, cD, cD, 16, EpiQKV{qkv, bias_cat});
  rope_kernel<<<cM, 256, 0, stream>>>(qkv, cosb, sinb, topk);
  vtrans<<<dim3(cK / 32, cHD / 32, cB * cKVH), tb, 0, stream>>>(qkv, vt);

  // fused flash attention (1D grid, XCD-chunked remap for KV L2 locality)
  flash_attn<<<1024, 256, 0, stream>>>(qkv, vt, attnout);

  // o-proj + gathered residual -> x (fp32)   [pair-mode pipeline]
  gemm256<128, 4, 2, 5, 2, EpiOProj><<<16 * (cD / 128), 512, 0, stream>>>(
      attnout, cD, wt_o, cD, cD, 16, EpiOProj{xbuf, hidden, topk});
  // rmsnorm2
  rmsnorm_rows<<<cM, 256, 0, stream>>>(xbuf, nullptr, ln2, hbuf);
  // fused gate+up -> act = silu(gate)*up   [8-phase m201-style schedule]
  gemm_gateup8<<<16 * (2 * cFF / 256), 512, 0, stream>>>(hbuf, wt_gu, actbuf);
  // down + residual + gating + scatter into d_out   [pair-mode pipeline]
  gemm256<128, 4, 2, 5, 2, EpiDown><<<16 * (cD / 128), 512, 0, stream>>>(
      actbuf, cFF, wt_d, cFF, cFF, 16, EpiDown{out, xbuf, hidden, topk, gating});
}